// Round 1
// baseline (411.263 us; speedup 1.0000x reference)
//
#include <hip/hip_runtime.h>

typedef unsigned int u32;
typedef unsigned long long u64;

#define NL 2048

__device__ __forceinline__ u32 umax_(u32 a, u32 b) { return a > b ? a : b; }

__device__ __forceinline__ u64 shfl_xor64(u64 v, int m) {
  int lo = __shfl_xor((int)(u32)v, m, 64);
  int hi = __shfl_xor((int)(u32)(v >> 32), m, 64);
  return ((u64)(u32)hi << 32) | (u32)lo;
}

// ---------------------------------------------------------------------------
// Kernel A: exact 32-NN per point (matches jax.lax.top_k(-d2, 32) incl. ties)
// block = 256 (4 waves), grid = 256. Block handles 64 queries of one batch.
// Wave w scans candidates [w*512, (w+1)*512), keeps per-thread top-32 in LDS.
// Final: per query, bitonic-sort the 128 partial entries on (key,idx) u64.
// Dynamic LDS: cand float4[2048] (32768B) + tkey u32[4*2080] + tidx u32[4*2080]
// = 99328 B.
// ---------------------------------------------------------------------------
__global__ __launch_bounds__(256) void knn_kernel(const float* __restrict__ frames,
                                                  int* __restrict__ idx32) {
  extern __shared__ char smraw[];
  float4* cand = (float4*)smraw;
  u32* tk = (u32*)(smraw + 2048 * 16);
  u32* ti = tk + 4 * 2080;

  const int b = blockIdx.x >> 5;
  const int qg = blockIdx.x & 31;
  const int tid = threadIdx.x;
  const int t = tid & 63;
  const int w = tid >> 6;

  // stage candidate coords + |c|^2
  for (int ii = 0; ii < 8; ii++) {
    int l = tid + ii * 256;
    float4 fr = *(const float4*)(frames + (size_t)(b * NL + l) * 12);
    float sq = fr.x * fr.x + fr.y * fr.y + fr.z * fr.z;
    cand[l] = make_float4(fr.x, fr.y, fr.z, sq);
  }
  __syncthreads();

  const int lq = qg * 64 + t;
  float4 me = cand[lq];

  u32* tkw = tk + w * 2080;
  u32* tiw = ti + w * 2080;
  const int j0 = w * 512;

  u32 gm[8];
#pragma unroll
  for (int i = 0; i < 8; i++) gm[i] = 0u;

  // warm-up: first 32 candidates fill slots 0..31 directly
#pragma unroll
  for (int jj = 0; jj < 32; jj++) {
    int j = j0 + jj;
    float4 c = cand[j];
    float dot = c.x * me.x + c.y * me.y + c.z * me.z;
    float d2 = (me.w + c.w) - 2.0f * dot;
    u32 kb = __float_as_uint(d2);
    u32 key = kb ^ ((u32)((int)kb >> 31) | 0x80000000u);
    tkw[jj * 65 + t] = key;
    tiw[jj * 65 + t] = (u32)j;
    gm[jj >> 2] = umax_(gm[jj >> 2], key);
  }
  u32 cm = umax_(umax_(umax_(gm[0], gm[1]), umax_(gm[2], gm[3])),
                 umax_(umax_(gm[4], gm[5]), umax_(gm[6], gm[7])));

  float4 c = cand[j0 + 32];
  for (int jj = 32; jj < 512; jj++) {
    float4 cnext = cand[j0 + ((jj + 1) & 511)];  // prefetch (wrap harmless)
    int j = j0 + jj;
    float dot = c.x * me.x + c.y * me.y + c.z * me.z;
    float d2 = (me.w + c.w) - 2.0f * dot;
    u32 kb = __float_as_uint(d2);
    u32 key = kb ^ ((u32)((int)kb >> 31) | 0x80000000u);
    if (key < cm) {
      // find victim group (gmax == cm)
      int grp = 0, eqc = 0;
#pragma unroll
      for (int i = 0; i < 8; i++) {
        bool e = (gm[i] == cm);
        if (e) grp = i;
        eqc += e ? 1 : 0;
      }
      u32 s0 = tkw[(grp * 4 + 0) * 65 + t];
      u32 s1 = tkw[(grp * 4 + 1) * 65 + t];
      u32 s2 = tkw[(grp * 4 + 2) * 65 + t];
      u32 s3 = tkw[(grp * 4 + 3) * 65 + t];
      int vs = 0, eqs = 0;
      {
        bool e0 = (s0 == cm), e1 = (s1 == cm), e2 = (s2 == cm), e3 = (s3 == cm);
        if (e1) vs = 1;
        if (e2) vs = 2;
        if (e3) vs = 3;
        eqs = (e0 ? 1 : 0) + (e1 ? 1 : 0) + (e2 ? 1 : 0) + (e3 ? 1 : 0);
      }
      if (eqc > 1 || eqs > 1) {
        // rare exact path: lexicographic (key, idx) max over all 32 slots
        u64 best = 0ull;
        int bs = 0;
        for (int s = 0; s < 32; s++) {
          u64 v = ((u64)tkw[s * 65 + t] << 32) | (u64)tiw[s * 65 + t];
          if (v > best) { best = v; bs = s; }
        }
        grp = bs >> 2;
        vs = bs & 3;
        s0 = tkw[(grp * 4 + 0) * 65 + t];
        s1 = tkw[(grp * 4 + 1) * 65 + t];
        s2 = tkw[(grp * 4 + 2) * 65 + t];
        s3 = tkw[(grp * 4 + 3) * 65 + t];
      }
      tkw[(grp * 4 + vs) * 65 + t] = key;
      tiw[(grp * 4 + vs) * 65 + t] = (u32)j;
      if (vs == 0) s0 = key;
      else if (vs == 1) s1 = key;
      else if (vs == 2) s2 = key;
      else s3 = key;
      u32 ng = umax_(umax_(s0, s1), umax_(s2, s3));
#pragma unroll
      for (int i = 0; i < 8; i++)
        if (i == grp) gm[i] = ng;
      cm = umax_(umax_(umax_(gm[0], gm[1]), umax_(gm[2], gm[3])),
                 umax_(umax_(gm[4], gm[5]), umax_(gm[6], gm[7])));
    }
    c = cnext;
  }
  __syncthreads();

  // merge: per query, bitonic sort 128 entries (2 per lane) ascending (key,idx)
  const int lane = t;
  for (int qq = 0; qq < 16; qq++) {
    int tq = w * 16 + qq;
    u64 f0 = ((u64)tk[lane * 65 + tq] << 32) | (u64)ti[lane * 65 + tq];
    u64 f1 = ((u64)tk[(lane + 64) * 65 + tq] << 32) | (u64)ti[(lane + 64) * 65 + tq];
    for (int k = 2; k <= 128; k <<= 1) {
      for (int j = k >> 1; j > 0; j >>= 1) {
        if (j == 64) {
          u64 lo = f0 < f1 ? f0 : f1;
          u64 hi = f0 < f1 ? f1 : f0;
          f0 = lo;
          f1 = hi;
        } else {
          bool lower = ((lane & j) == 0);
          bool asc0 = ((lane & k) == 0);
          bool asc1 = (((lane + 64) & k) == 0);
          u64 p0 = shfl_xor64(f0, j);
          u64 p1 = shfl_xor64(f1, j);
          f0 = ((f0 < p0) == (lower == asc0)) ? f0 : p0;
          f1 = ((f1 < p1) == (lower == asc1)) ? f1 : p1;
        }
      }
    }
    if (lane < 32) {
      int row = b * NL + qg * 64 + tq;
      idx32[row * 32 + lane] = (int)(f0 & 0xFFFFFFFFull);
    }
  }
}

// ---------------------------------------------------------------------------
// Kernel B: stage-1 coords + gaussians + outer product (per point: 640 floats)
// block = 256 (4 points x 64 lanes), grid = 4096
// ---------------------------------------------------------------------------
__global__ __launch_bounds__(256) void stage1_kernel(
    const float* __restrict__ frames, const float* __restrict__ attrs,
    const int* __restrict__ aaidx, const float* __restrict__ cen1,
    const float* __restrict__ prec1, const int* __restrict__ idx32,
    float* __restrict__ outer) {
  __shared__ float sPrec[1568];
  __shared__ float sCen[224];
  __shared__ float sCoord[4 * 16 * 8];
  __shared__ float sAttr[4 * 16 * 20];
  __shared__ float sG1[4 * 16 * 33];
  const int tid = threadIdx.x;
  for (int i = tid; i < 1568; i += 256) sPrec[i] = prec1[i];
  if (tid < 224) sCen[tid] = cen1[tid];
  const int pt = tid >> 6, lane = tid & 63;
  const int pid = blockIdx.x * 4 + pt;
  const int b = pid >> 11;
  __syncthreads();

  if (lane < 16) {
    int n = lane;
    int j = idx32[pid * 32 + n];
    int jg = b * NL + j;
    const float* fs = frames + (size_t)pid * 12;
    const float* fj = frames + (size_t)jg * 12;
    float4 A0 = *(const float4*)(fs);
    float4 A1 = *(const float4*)(fs + 4);
    float4 A2 = *(const float4*)(fs + 8);
    float4 B0 = *(const float4*)(fj);
    float4 B2 = *(const float4*)(fj + 8);
    float dx = B0.x - A0.x, dy = B0.y - A0.y, dzc = B0.z - A0.z;
    float a0x = A0.w, a0y = A1.x, a0z = A1.y;
    float a1x = A1.z, a1y = A1.w, a1z = A2.x;
    float a2x = A2.y, a2y = A2.z, a2z = A2.w;  // z_i == axes[2]
    float zjx = B2.y, zjy = B2.z, zjz = B2.w;
    float dd = dx * dx + dy * dy + dzc * dzc + 1e-12f;
    float dist = sqrtf(dd);
    float e0 = dx * a0x + dy * a0y + dzc * a0z;
    float e1 = dx * a1x + dy * a1y + dzc * a1z;
    float e2 = dx * a2x + dy * a2y + dzc * a2z;
    float zz = a2x * zjx + a2y * zjy + a2z * zjz;
    float dzv = (dx * zjx + dy * zjy + dzc * zjz) / dist;
    float zdv = (a2x * dx + a2y * dy + a2z * dzc) / dist;
    float si = (float)aaidx[pid];
    float sj = (float)aaidx[jg];
    float idist = fminf(fabsf(sj - si), 8.0f);
    float* cr = sCoord + pt * 128 + n * 8;
    cr[0] = e0; cr[1] = e1; cr[2] = e2; cr[3] = idist;
    cr[4] = zz; cr[5] = dzv; cr[6] = zdv;
    const float* ar = attrs + (size_t)jg * 20;
    float* aw = sAttr + pt * 320 + n * 20;
#pragma unroll
    for (int q = 0; q < 5; q++) *(float4*)(aw + q * 4) = *(const float4*)(ar + q * 4);
  }
  __syncthreads();
  {
    const int g = lane & 31, nh = lane >> 5;
    float pr[7][7], cn[7];
#pragma unroll
    for (int d = 0; d < 7; d++) {
      cn[d] = sCen[d * 32 + g];
#pragma unroll
      for (int kk = 0; kk < 7; kk++) pr[d][kk] = sPrec[(d * 7 + kk) * 32 + g];
    }
#pragma unroll
    for (int i = 0; i < 8; i++) {
      int n = nh * 8 + i;
      const float* cr = sCoord + pt * 128 + n * 8;
      float df[7];
#pragma unroll
      for (int d = 0; d < 7; d++) df[d] = cr[d] - cn[d];
      float s = 0.0f;
#pragma unroll
      for (int kk = 0; kk < 7; kk++) {
        float y = 0.0f;
#pragma unroll
        for (int d = 0; d < 7; d++) y = fmaf(df[d], pr[d][kk], y);
        s = fmaf(y, y, s);
      }
      sG1[pt * 528 + n * 33 + g] = __expf(-0.5f * s);
    }
  }
  __syncthreads();
#pragma unroll
  for (int i = 0; i < 10; i++) {
    int o = lane + 64 * i;
    int g = o / 20;
    int h = o - g * 20;
    float acc = 0.0f;
#pragma unroll
    for (int n = 0; n < 16; n++)
      acc = fmaf(sG1[pt * 528 + n * 33 + g], sAttr[pt * 320 + n * 20 + h], acc);
    outer[(size_t)pid * 640 + o] = acc;
  }
}

// ---------------------------------------------------------------------------
// Kernel C: filt GEMM (16384x640 @ 640x128) + relu + emb (128->32) + 5 heads,
// fully fused in LDS. block = 256, grid = 256 (64 points per block).
// head8 layout per point: [catt, nf0, nf1, 0, beta, satt, 0, 0]
// ---------------------------------------------------------------------------
__global__ __launch_bounds__(256) void gemm_kernel(
    const float* __restrict__ outer, const float* __restrict__ opW,
    const float* __restrict__ opB, const float* __restrict__ embW,
    const float* __restrict__ embB, const float* __restrict__ betaW,
    const float* __restrict__ betaB, const float* __restrict__ sattW,
    const float* __restrict__ sattB, const float* __restrict__ cattW,
    const float* __restrict__ cattB, const float* __restrict__ nodW,
    const float* __restrict__ nodB, float* __restrict__ head8) {
  __shared__ float sm[15136];
  const int tid = threadIdx.x;
  const int p0 = blockIdx.x * 64;
  const int og = tid & 15, pg = tid >> 4;
  const int o0 = og * 8, pb = pg * 4;
  float acc[4][8];
#pragma unroll
  for (int p = 0; p < 4; p++) {
#pragma unroll
    for (int o = 0; o < 8; o++) acc[p][o] = 0.0f;
  }

  for (int cc = 0; cc < 10; cc++) {
#pragma unroll
    for (int jj = 0; jj < 4; jj++) {
      int f = tid + 256 * jj;
      int p = f >> 4, q = f & 15;
      float4 v = *(const float4*)(outer + (size_t)(p0 + p) * 640 + cc * 64 + q * 4);
      *(float4*)(sm + p * 68 + q * 4) = v;
    }
#pragma unroll
    for (int jj = 0; jj < 8; jj++) {
      int f = tid + 256 * jj;
      int k = f >> 5, oq = f & 31;
      float4 v = *(const float4*)(opW + (size_t)(cc * 64 + k) * 128 + oq * 4);
      *(float4*)(sm + 4352 + k * 132 + oq * 4) = v;
    }
    __syncthreads();
#pragma unroll 4
    for (int k = 0; k < 64; k++) {
      float4 w0 = *(const float4*)(sm + 4352 + k * 132 + o0);
      float4 w1 = *(const float4*)(sm + 4352 + k * 132 + o0 + 4);
      float wv[8];
      wv[0] = w0.x; wv[1] = w0.y; wv[2] = w0.z; wv[3] = w0.w;
      wv[4] = w1.x; wv[5] = w1.y; wv[6] = w1.z; wv[7] = w1.w;
#pragma unroll
      for (int p = 0; p < 4; p++) {
        float a = sm[(pb + p) * 68 + k];
#pragma unroll
        for (int o = 0; o < 8; o++) acc[p][o] = fmaf(a, wv[o], acc[p][o]);
      }
    }
    __syncthreads();
  }

  // epilogue: bias + relu -> fTile (pitch 133 at sm[0..8512))
  {
    float4 b0 = *(const float4*)(opB + o0);
    float4 b1 = *(const float4*)(opB + o0 + 4);
    float bias[8] = {b0.x, b0.y, b0.z, b0.w, b1.x, b1.y, b1.z, b1.w};
#pragma unroll
    for (int p = 0; p < 4; p++) {
#pragma unroll
      for (int oo = 0; oo < 8; oo++)
        sm[(pb + p) * 133 + o0 + oo] = fmaxf(acc[p][oo] + bias[oo], 0.0f);
    }
  }
  for (int i = tid; i < 4096; i += 256) sm[8512 + i] = embW[i];
  if (tid < 32) {
    sm[14976 + tid * 5 + 0] = betaW[tid];
    sm[14976 + tid * 5 + 1] = sattW[tid];
    sm[14976 + tid * 5 + 2] = cattW[tid];
    sm[14976 + tid * 5 + 3] = nodW[tid * 2];
    sm[14976 + tid * 5 + 4] = nodW[tid * 2 + 1];
  }
  __syncthreads();

  // emb = relu(f @ embW + embB): 64p x 32o; thread = (pe, oge) -> 8 outs
  {
    const int pe = tid >> 2, oge = tid & 3, oe = oge * 8;
    float ea[8];
#pragma unroll
    for (int o = 0; o < 8; o++) ea[o] = 0.0f;
#pragma unroll 4
    for (int k = 0; k < 128; k++) {
      float fv = sm[pe * 133 + k];
      float4 w0 = *(const float4*)(sm + 8512 + k * 32 + oe);
      float4 w1 = *(const float4*)(sm + 8512 + k * 32 + oe + 4);
      ea[0] = fmaf(fv, w0.x, ea[0]);
      ea[1] = fmaf(fv, w0.y, ea[1]);
      ea[2] = fmaf(fv, w0.z, ea[2]);
      ea[3] = fmaf(fv, w0.w, ea[3]);
      ea[4] = fmaf(fv, w1.x, ea[4]);
      ea[5] = fmaf(fv, w1.y, ea[5]);
      ea[6] = fmaf(fv, w1.z, ea[6]);
      ea[7] = fmaf(fv, w1.w, ea[7]);
    }
    float4 eb0 = *(const float4*)(embB + oe);
    float4 eb1 = *(const float4*)(embB + oe + 4);
    float ebv[8] = {eb0.x, eb0.y, eb0.z, eb0.w, eb1.x, eb1.y, eb1.z, eb1.w};
#pragma unroll
    for (int o = 0; o < 8; o++)
      sm[12608 + pe * 37 + oe + o] = fmaxf(ea[o] + ebv[o], 0.0f);
  }
  __syncthreads();
  if (tid < 64) {
    float a0 = 0, a1 = 0, a2 = 0, a3 = 0, a4 = 0;
#pragma unroll 8
    for (int k = 0; k < 32; k++) {
      float e = sm[12608 + tid * 37 + k];
      const float* hw = sm + 14976 + k * 5;
      a0 = fmaf(e, hw[0], a0);
      a1 = fmaf(e, hw[1], a1);
      a2 = fmaf(e, hw[2], a2);
      a3 = fmaf(e, hw[3], a3);
      a4 = fmaf(e, hw[4], a4);
    }
    float* hb = head8 + (size_t)(p0 + tid) * 8;
    hb[0] = fmaxf(a2 + cattB[0], 0.0f);
    hb[1] = fmaxf(a3 + nodB[0], 0.0f);
    hb[2] = fmaxf(a4 + nodB[1], 0.0f);
    hb[3] = 0.0f;
    hb[4] = fmaxf(a0 + betaB[0], 0.0f);
    hb[5] = fmaxf(a1 + sattB[0], 0.0f);
    hb[6] = 0.0f;
    hb[7] = 0.0f;
  }
}

// ---------------------------------------------------------------------------
// Kernel E: stage-2 coords + gaussians + gw + softmax attention -> out (B,L,2)
// block = 256 (4 points x 64 lanes), grid = 4096
// ---------------------------------------------------------------------------
__global__ __launch_bounds__(256) void stage2_kernel(
    const float* __restrict__ frames, const int* __restrict__ aaidx,
    const float* __restrict__ cen2, const float* __restrict__ prec2,
    const float* __restrict__ emb2W, const float* __restrict__ emb2B,
    const int* __restrict__ idx32, const float* __restrict__ head8,
    float* __restrict__ out) {
  __shared__ float sPrec[800];
  __shared__ float sCen[160];
  __shared__ float sW2[32];
  __shared__ float sCoord[4 * 32 * 5];
  __shared__ float sG2[4 * 32 * 33];
  const int tid = threadIdx.x;
  for (int i = tid; i < 800; i += 256) sPrec[i] = prec2[i];
  if (tid < 160) sCen[tid] = cen2[tid];
  if (tid < 32) sW2[tid] = emb2W[tid];
  const int pt = tid >> 6, lane = tid & 63;
  const int pid = blockIdx.x * 4 + pt;
  const int b = pid >> 11;
  __syncthreads();

  float4 hv = make_float4(0.f, 0.f, 0.f, 0.f);
  float betaS = 0.f, sattS = 0.f;
  if (lane < 32) {
    int n = lane;
    int j = idx32[pid * 32 + n];
    int jg = b * NL + j;
    const float* fs = frames + (size_t)pid * 12;
    const float* fj = frames + (size_t)jg * 12;
    float4 A0 = *(const float4*)(fs);
    float4 A2 = *(const float4*)(fs + 8);
    float4 B0 = *(const float4*)(fj);
    float4 B2 = *(const float4*)(fj + 8);
    float dx = B0.x - A0.x, dy = B0.y - A0.y, dzc = B0.z - A0.z;
    float a2x = A2.y, a2y = A2.z, a2z = A2.w;  // z_i
    float zjx = B2.y, zjy = B2.z, zjz = B2.w;
    float dd = dx * dx + dy * dy + dzc * dzc + 1e-12f;
    float dist = sqrtf(dd);
    float zz = a2x * zjx + a2y * zjy + a2z * zjz;
    float dzv = (dx * zjx + dy * zjy + dzc * zjz) / dist;
    float zdv = (a2x * dx + a2y * dy + a2z * dzc) / dist;
    float si = (float)aaidx[pid];
    float sj = (float)aaidx[jg];
    float idist = fminf(fabsf(sj - si), 8.0f);
    float* cr = sCoord + pt * 160 + n * 5;
    cr[0] = dist; cr[1] = zz; cr[2] = dzv; cr[3] = zdv; cr[4] = idist;
    hv = *(const float4*)(head8 + (size_t)jg * 8);  // catt, nf0, nf1
    betaS = head8[(size_t)pid * 8 + 4];
    sattS = head8[(size_t)pid * 8 + 5];
  }
  __syncthreads();
  {
    const int g = lane & 31, nh = lane >> 5;
    float pr[5][5], cn[5];
#pragma unroll
    for (int d = 0; d < 5; d++) {
      cn[d] = sCen[d * 32 + g];
#pragma unroll
      for (int kk = 0; kk < 5; kk++) pr[d][kk] = sPrec[(d * 5 + kk) * 32 + g];
    }
#pragma unroll
    for (int i = 0; i < 16; i++) {
      int n = nh * 16 + i;
      const float* cr = sCoord + pt * 160 + n * 5;
      float df[5];
#pragma unroll
      for (int d = 0; d < 5; d++) df[d] = cr[d] - cn[d];
      float s = 0.0f;
#pragma unroll
      for (int kk = 0; kk < 5; kk++) {
        float y = 0.0f;
#pragma unroll
        for (int d = 0; d < 5; d++) y = fmaf(df[d], pr[d][kk], y);
        s = fmaf(y, y, s);
      }
      sG2[pt * 1056 + n * 33 + g] = __expf(-0.5f * s);
    }
  }
  __syncthreads();
  if (lane < 32) {
    int n = lane;
    float gw = emb2B[0];
#pragma unroll 8
    for (int g = 0; g < 32; g++) gw = fmaf(sG2[pt * 1056 + n * 33 + g], sW2[g], gw);
    gw = fmaxf(gw, 0.0f);
    float e = (n == 0) ? sattS : hv.x;
    float logit = betaS * e;
    float m = logit;
#pragma unroll
    for (int d = 1; d < 32; d <<= 1) m = fmaxf(m, __shfl_xor(m, d, 64));
    float wv = gw * __expf(logit - m);
    float S = wv;
#pragma unroll
    for (int d = 1; d < 32; d <<= 1) S += __shfl_xor(S, d, 64);
    float a = wv / (S + 1e-6f);
    float o0 = a * hv.y, o1 = a * hv.z;
#pragma unroll
    for (int d = 1; d < 32; d <<= 1) {
      o0 += __shfl_xor(o0, d, 64);
      o1 += __shfl_xor(o1, d, 64);
    }
    if (n == 0) {
      out[pid * 2 + 0] = o0;
      out[pid * 2 + 1] = o1;
    }
  }
}

// ---------------------------------------------------------------------------
extern "C" void kernel_launch(void* const* d_in, const int* in_sizes, int n_in,
                              void* d_out, int out_size, void* d_ws, size_t ws_size,
                              hipStream_t stream) {
  const float* attrs = (const float*)d_in[0];
  const float* frames = (const float*)d_in[1];
  const int* aaidx = (const int*)d_in[2];
  const float* cen1 = (const float*)d_in[3];
  const float* prec1 = (const float*)d_in[4];
  const float* opW = (const float*)d_in[5];
  const float* opB = (const float*)d_in[6];
  const float* embW = (const float*)d_in[7];
  const float* embB = (const float*)d_in[8];
  const float* betaW = (const float*)d_in[9];
  const float* betaB = (const float*)d_in[10];
  const float* sattW = (const float*)d_in[11];
  const float* sattB = (const float*)d_in[12];
  const float* cattW = (const float*)d_in[13];
  const float* cattB = (const float*)d_in[14];
  const float* nodW = (const float*)d_in[15];
  const float* nodB = (const float*)d_in[16];
  const float* cen2 = (const float*)d_in[17];
  const float* prec2 = (const float*)d_in[18];
  const float* emb2W = (const float*)d_in[19];
  const float* emb2B = (const float*)d_in[20];
  float* out = (float*)d_out;

  char* ws = (char*)d_ws;
  int* idx32 = (int*)ws;                                   // 16384*32*4  = 2 MiB
  float* outer = (float*)(ws + 2097152);                   // 16384*640*4 = 40 MiB
  float* head8 = (float*)(ws + 2097152 + 41943040);        // 16384*8*4   = 512 KiB

  // knn needs 99328 B dynamic LDS (> 64 KiB default); opt in every call
  // (idempotent, not a stream op -> safe under graph capture).
  (void)hipFuncSetAttribute((const void*)knn_kernel,
                            hipFuncAttributeMaxDynamicSharedMemorySize, 99328);

  knn_kernel<<<dim3(256), dim3(256), 99328, stream>>>(frames, idx32);
  stage1_kernel<<<dim3(4096), dim3(256), 0, stream>>>(frames, attrs, aaidx, cen1,
                                                      prec1, idx32, outer);
  gemm_kernel<<<dim3(256), dim3(256), 0, stream>>>(outer, opW, opB, embW, embB,
                                                   betaW, betaB, sattW, sattB,
                                                   cattW, cattB, nodW, nodB, head8);
  stage2_kernel<<<dim3(4096), dim3(256), 0, stream>>>(frames, aaidx, cen2, prec2,
                                                      emb2W, emb2B, idx32, head8, out);
}

// Round 2
// 243.110 us; speedup vs baseline: 1.6917x; 1.6917x over previous
//
#include <hip/hip_runtime.h>

typedef unsigned int u32;
typedef unsigned long long u64;

#define NL 2048

__device__ __forceinline__ u64 shfl_xor64(u64 v, int m) {
  int lo = __shfl_xor((int)(u32)v, m, 64);
  int hi = __shfl_xor((int)(u32)(v >> 32), m, 64);
  return ((u64)(u32)hi << 32) | (u32)lo;
}

// full ascending bitonic sort of 64 u32 across the wave (1 per lane)
__device__ __forceinline__ u32 sort64_u32(u32 v, int lane) {
#pragma unroll
  for (int k = 2; k <= 64; k <<= 1) {
#pragma unroll
    for (int j = k >> 1; j > 0; j >>= 1) {
      u32 p = (u32)__shfl_xor((int)v, j, 64);
      bool lower = ((lane & j) == 0);
      bool asc = ((lane & k) == 0);
      u32 lo = v < p ? v : p;
      u32 hi = v < p ? p : v;
      v = (lower == asc) ? lo : hi;
    }
  }
  return v;
}

// full ascending bitonic sort of 128 u64 across the wave (2 per lane).
// sequence position: f0 -> lane, f1 -> lane+64. (validated in round 0)
__device__ __forceinline__ void sort128_u64(u64& f0, u64& f1, int lane) {
  for (int k = 2; k <= 128; k <<= 1) {
    for (int j = k >> 1; j > 0; j >>= 1) {
      if (j == 64) {
        u64 lo = f0 < f1 ? f0 : f1;
        u64 hi = f0 < f1 ? f1 : f0;
        f0 = lo;
        f1 = hi;
      } else {
        bool lower = ((lane & j) == 0);
        bool asc0 = ((lane & k) == 0);
        bool asc1 = (((lane + 64) & k) == 0);
        u64 p0 = shfl_xor64(f0, j);
        u64 p1 = shfl_xor64(f1, j);
        f0 = ((f0 < p0) == (lower == asc0)) ? f0 : p0;
        f1 = ((f1 < p1) == (lower == asc1)) ? f1 : p1;
      }
    }
  }
}

// ---------------------------------------------------------------------------
// Kernel A (v2): exact 32-NN, threshold + compact + sort.
// block = 512 (8 waves = 8 queries), grid = 2048. One wave per query.
// Per lane: 32 candidates (stride 64), keys in registers.
// T0 = 32nd smallest of the 64 lane-minima (valid upper bound on the true
// 32nd-smallest key: the 32 smallest lane-minima are 32 distinct elements).
// Compact keys<=T0 (E[count]~44) into LDS, exact (key,idx) bitonic select.
// ---------------------------------------------------------------------------
__global__ __launch_bounds__(512) void knn_kernel(const float* __restrict__ frames,
                                                  int* __restrict__ idx32) {
  __shared__ float4 cand[2048];
  __shared__ u64 comp[8][256];
  const int tid = threadIdx.x;
  const int w = tid >> 6, lane = tid & 63;
  const int query = blockIdx.x * 8 + w;
  const int b = query >> 11, lq = query & (NL - 1);

#pragma unroll
  for (int i = 0; i < 4; i++) {
    int l = tid + i * 512;
    const float* fp = frames + (size_t)(b * NL + l) * 12;
    float4 fr = *(const float4*)fp;
    cand[l] = make_float4(fr.x, fr.y, fr.z,
                          fr.x * fr.x + fr.y * fr.y + fr.z * fr.z);
  }
  __syncthreads();

  float4 me = cand[lq];
  u32 k[32];
  u32 m = 0xFFFFFFFFu;
#pragma unroll
  for (int i = 0; i < 32; i++) {
    float4 c = cand[i * 64 + lane];
    float dot = c.x * me.x + c.y * me.y + c.z * me.z;
    float d2 = (me.w + c.w) - 2.0f * dot;
    u32 kb = __float_as_uint(d2);
    u32 key = kb ^ ((u32)((int)kb >> 31) | 0x80000000u);
    k[i] = key;
    m = key < m ? key : m;
  }

  u32 ms = sort64_u32(m, lane);
  u32 T0 = (u32)__shfl((int)ms, 31, 64);

  int base = 0;
#pragma unroll
  for (int i = 0; i < 32; i++) {
    bool flag = (k[i] <= T0);
    u64 mask = __ballot(flag);
    if (flag) {
      u32 rank = __builtin_amdgcn_mbcnt_hi(
          (u32)(mask >> 32), __builtin_amdgcn_mbcnt_lo((u32)mask, 0u));
      int pos = base + (int)rank;
      if (pos < 256) comp[w][pos] = ((u64)k[i] << 32) | (u32)(i * 64 + lane);
    }
    base += (int)__popcll(mask);
  }
  int cnt = base < 256 ? base : 256;
  __syncthreads();  // uniform point: orders in-wave LDS writes before reads

  u64 f0 = ~0ull;
  for (int c = 0; c * 64 < cnt; c++) {
    int p = c * 64 + lane;
    u64 f1 = (p < cnt) ? comp[w][p] : ~0ull;
    sort128_u64(f0, f1, lane);
    f0 = (lane < 32) ? f0 : ~0ull;
  }
  if (lane < 32)
    idx32[(size_t)query * 32 + lane] = (int)(f0 & 0xFFFFFFFFull);
}

// ---------------------------------------------------------------------------
// Kernel B: stage-1 coords + gaussians + outer product (per point: 640 floats)
// block = 256 (4 points x 64 lanes), grid = 4096
// ---------------------------------------------------------------------------
__global__ __launch_bounds__(256) void stage1_kernel(
    const float* __restrict__ frames, const float* __restrict__ attrs,
    const int* __restrict__ aaidx, const float* __restrict__ cen1,
    const float* __restrict__ prec1, const int* __restrict__ idx32,
    float* __restrict__ outer) {
  __shared__ float sPrec[1568];
  __shared__ float sCen[224];
  __shared__ float sCoord[4 * 16 * 8];
  __shared__ float sAttr[4 * 16 * 20];
  __shared__ float sG1[4 * 16 * 33];
  const int tid = threadIdx.x;
  for (int i = tid; i < 1568; i += 256) sPrec[i] = prec1[i];
  if (tid < 224) sCen[tid] = cen1[tid];
  const int pt = tid >> 6, lane = tid & 63;
  const int pid = blockIdx.x * 4 + pt;
  const int b = pid >> 11;
  __syncthreads();

  if (lane < 16) {
    int n = lane;
    int j = idx32[pid * 32 + n];
    int jg = b * NL + j;
    const float* fs = frames + (size_t)pid * 12;
    const float* fj = frames + (size_t)jg * 12;
    float4 A0 = *(const float4*)(fs);
    float4 A1 = *(const float4*)(fs + 4);
    float4 A2 = *(const float4*)(fs + 8);
    float4 B0 = *(const float4*)(fj);
    float4 B2 = *(const float4*)(fj + 8);
    float dx = B0.x - A0.x, dy = B0.y - A0.y, dzc = B0.z - A0.z;
    float a0x = A0.w, a0y = A1.x, a0z = A1.y;
    float a1x = A1.z, a1y = A1.w, a1z = A2.x;
    float a2x = A2.y, a2y = A2.z, a2z = A2.w;  // z_i == axes[2]
    float zjx = B2.y, zjy = B2.z, zjz = B2.w;
    float dd = dx * dx + dy * dy + dzc * dzc + 1e-12f;
    float dist = sqrtf(dd);
    float e0 = dx * a0x + dy * a0y + dzc * a0z;
    float e1 = dx * a1x + dy * a1y + dzc * a1z;
    float e2 = dx * a2x + dy * a2y + dzc * a2z;
    float zz = a2x * zjx + a2y * zjy + a2z * zjz;
    float dzv = (dx * zjx + dy * zjy + dzc * zjz) / dist;
    float zdv = (a2x * dx + a2y * dy + a2z * dzc) / dist;
    float si = (float)aaidx[pid];
    float sj = (float)aaidx[jg];
    float idist = fminf(fabsf(sj - si), 8.0f);
    float* cr = sCoord + pt * 128 + n * 8;
    cr[0] = e0; cr[1] = e1; cr[2] = e2; cr[3] = idist;
    cr[4] = zz; cr[5] = dzv; cr[6] = zdv;
    const float* ar = attrs + (size_t)jg * 20;
    float* aw = sAttr + pt * 320 + n * 20;
#pragma unroll
    for (int q = 0; q < 5; q++) *(float4*)(aw + q * 4) = *(const float4*)(ar + q * 4);
  }
  __syncthreads();
  {
    const int g = lane & 31, nh = lane >> 5;
    float pr[7][7], cn[7];
#pragma unroll
    for (int d = 0; d < 7; d++) {
      cn[d] = sCen[d * 32 + g];
#pragma unroll
      for (int kk = 0; kk < 7; kk++) pr[d][kk] = sPrec[(d * 7 + kk) * 32 + g];
    }
#pragma unroll
    for (int i = 0; i < 8; i++) {
      int n = nh * 8 + i;
      const float* cr = sCoord + pt * 128 + n * 8;
      float df[7];
#pragma unroll
      for (int d = 0; d < 7; d++) df[d] = cr[d] - cn[d];
      float s = 0.0f;
#pragma unroll
      for (int kk = 0; kk < 7; kk++) {
        float y = 0.0f;
#pragma unroll
        for (int d = 0; d < 7; d++) y = fmaf(df[d], pr[d][kk], y);
        s = fmaf(y, y, s);
      }
      sG1[pt * 528 + n * 33 + g] = __expf(-0.5f * s);
    }
  }
  __syncthreads();
#pragma unroll
  for (int i = 0; i < 10; i++) {
    int o = lane + 64 * i;
    int g = o / 20;
    int h = o - g * 20;
    float acc = 0.0f;
#pragma unroll
    for (int n = 0; n < 16; n++)
      acc = fmaf(sG1[pt * 528 + n * 33 + g], sAttr[pt * 320 + n * 20 + h], acc);
    outer[(size_t)pid * 640 + o] = acc;
  }
}

// ---------------------------------------------------------------------------
// Kernel C: filt GEMM (16384x640 @ 640x128) + relu + emb (128->32) + 5 heads,
// fully fused in LDS. block = 256, grid = 256 (64 points per block).
// head8 layout per point: [catt, nf0, nf1, 0, beta, satt, 0, 0]
// ---------------------------------------------------------------------------
__global__ __launch_bounds__(256) void gemm_kernel(
    const float* __restrict__ outer, const float* __restrict__ opW,
    const float* __restrict__ opB, const float* __restrict__ embW,
    const float* __restrict__ embB, const float* __restrict__ betaW,
    const float* __restrict__ betaB, const float* __restrict__ sattW,
    const float* __restrict__ sattB, const float* __restrict__ cattW,
    const float* __restrict__ cattB, const float* __restrict__ nodW,
    const float* __restrict__ nodB, float* __restrict__ head8) {
  __shared__ float sm[15136];
  const int tid = threadIdx.x;
  const int p0 = blockIdx.x * 64;
  const int og = tid & 15, pg = tid >> 4;
  const int o0 = og * 8, pb = pg * 4;
  float acc[4][8];
#pragma unroll
  for (int p = 0; p < 4; p++) {
#pragma unroll
    for (int o = 0; o < 8; o++) acc[p][o] = 0.0f;
  }

  for (int cc = 0; cc < 10; cc++) {
#pragma unroll
    for (int jj = 0; jj < 4; jj++) {
      int f = tid + 256 * jj;
      int p = f >> 4, q = f & 15;
      float4 v = *(const float4*)(outer + (size_t)(p0 + p) * 640 + cc * 64 + q * 4);
      *(float4*)(sm + p * 68 + q * 4) = v;
    }
#pragma unroll
    for (int jj = 0; jj < 8; jj++) {
      int f = tid + 256 * jj;
      int k = f >> 5, oq = f & 31;
      float4 v = *(const float4*)(opW + (size_t)(cc * 64 + k) * 128 + oq * 4);
      *(float4*)(sm + 4352 + k * 132 + oq * 4) = v;
    }
    __syncthreads();
#pragma unroll 4
    for (int k = 0; k < 64; k++) {
      float4 w0 = *(const float4*)(sm + 4352 + k * 132 + o0);
      float4 w1 = *(const float4*)(sm + 4352 + k * 132 + o0 + 4);
      float wv[8];
      wv[0] = w0.x; wv[1] = w0.y; wv[2] = w0.z; wv[3] = w0.w;
      wv[4] = w1.x; wv[5] = w1.y; wv[6] = w1.z; wv[7] = w1.w;
#pragma unroll
      for (int p = 0; p < 4; p++) {
        float a = sm[(pb + p) * 68 + k];
#pragma unroll
        for (int o = 0; o < 8; o++) acc[p][o] = fmaf(a, wv[o], acc[p][o]);
      }
    }
    __syncthreads();
  }

  // epilogue: bias + relu -> fTile (pitch 133 at sm[0..8512))
  {
    float4 b0 = *(const float4*)(opB + o0);
    float4 b1 = *(const float4*)(opB + o0 + 4);
    float bias[8] = {b0.x, b0.y, b0.z, b0.w, b1.x, b1.y, b1.z, b1.w};
#pragma unroll
    for (int p = 0; p < 4; p++) {
#pragma unroll
      for (int oo = 0; oo < 8; oo++)
        sm[(pb + p) * 133 + o0 + oo] = fmaxf(acc[p][oo] + bias[oo], 0.0f);
    }
  }
  for (int i = tid; i < 4096; i += 256) sm[8512 + i] = embW[i];
  if (tid < 32) {
    sm[14976 + tid * 5 + 0] = betaW[tid];
    sm[14976 + tid * 5 + 1] = sattW[tid];
    sm[14976 + tid * 5 + 2] = cattW[tid];
    sm[14976 + tid * 5 + 3] = nodW[tid * 2];
    sm[14976 + tid * 5 + 4] = nodW[tid * 2 + 1];
  }
  __syncthreads();

  // emb = relu(f @ embW + embB): 64p x 32o; thread = (pe, oge) -> 8 outs
  {
    const int pe = tid >> 2, oge = tid & 3, oe = oge * 8;
    float ea[8];
#pragma unroll
    for (int o = 0; o < 8; o++) ea[o] = 0.0f;
#pragma unroll 4
    for (int k = 0; k < 128; k++) {
      float fv = sm[pe * 133 + k];
      float4 w0 = *(const float4*)(sm + 8512 + k * 32 + oe);
      float4 w1 = *(const float4*)(sm + 8512 + k * 32 + oe + 4);
      ea[0] = fmaf(fv, w0.x, ea[0]);
      ea[1] = fmaf(fv, w0.y, ea[1]);
      ea[2] = fmaf(fv, w0.z, ea[2]);
      ea[3] = fmaf(fv, w0.w, ea[3]);
      ea[4] = fmaf(fv, w1.x, ea[4]);
      ea[5] = fmaf(fv, w1.y, ea[5]);
      ea[6] = fmaf(fv, w1.z, ea[6]);
      ea[7] = fmaf(fv, w1.w, ea[7]);
    }
    float4 eb0 = *(const float4*)(embB + oe);
    float4 eb1 = *(const float4*)(embB + oe + 4);
    float ebv[8] = {eb0.x, eb0.y, eb0.z, eb0.w, eb1.x, eb1.y, eb1.z, eb1.w};
#pragma unroll
    for (int o = 0; o < 8; o++)
      sm[12608 + pe * 37 + oe + o] = fmaxf(ea[o] + ebv[o], 0.0f);
  }
  __syncthreads();
  if (tid < 64) {
    float a0 = 0, a1 = 0, a2 = 0, a3 = 0, a4 = 0;
#pragma unroll 8
    for (int k = 0; k < 32; k++) {
      float e = sm[12608 + tid * 37 + k];
      const float* hw = sm + 14976 + k * 5;
      a0 = fmaf(e, hw[0], a0);
      a1 = fmaf(e, hw[1], a1);
      a2 = fmaf(e, hw[2], a2);
      a3 = fmaf(e, hw[3], a3);
      a4 = fmaf(e, hw[4], a4);
    }
    float* hb = head8 + (size_t)(p0 + tid) * 8;
    hb[0] = fmaxf(a2 + cattB[0], 0.0f);
    hb[1] = fmaxf(a3 + nodB[0], 0.0f);
    hb[2] = fmaxf(a4 + nodB[1], 0.0f);
    hb[3] = 0.0f;
    hb[4] = fmaxf(a0 + betaB[0], 0.0f);
    hb[5] = fmaxf(a1 + sattB[0], 0.0f);
    hb[6] = 0.0f;
    hb[7] = 0.0f;
  }
}

// ---------------------------------------------------------------------------
// Kernel E: stage-2 coords + gaussians + gw + softmax attention -> out (B,L,2)
// block = 256 (4 points x 64 lanes), grid = 4096
// ---------------------------------------------------------------------------
__global__ __launch_bounds__(256) void stage2_kernel(
    const float* __restrict__ frames, const int* __restrict__ aaidx,
    const float* __restrict__ cen2, const float* __restrict__ prec2,
    const float* __restrict__ emb2W, const float* __restrict__ emb2B,
    const int* __restrict__ idx32, const float* __restrict__ head8,
    float* __restrict__ out) {
  __shared__ float sPrec[800];
  __shared__ float sCen[160];
  __shared__ float sW2[32];
  __shared__ float sCoord[4 * 32 * 5];
  __shared__ float sG2[4 * 32 * 33];
  const int tid = threadIdx.x;
  for (int i = tid; i < 800; i += 256) sPrec[i] = prec2[i];
  if (tid < 160) sCen[tid] = cen2[tid];
  if (tid < 32) sW2[tid] = emb2W[tid];
  const int pt = tid >> 6, lane = tid & 63;
  const int pid = blockIdx.x * 4 + pt;
  const int b = pid >> 11;
  __syncthreads();

  float4 hv = make_float4(0.f, 0.f, 0.f, 0.f);
  float betaS = 0.f, sattS = 0.f;
  if (lane < 32) {
    int n = lane;
    int j = idx32[pid * 32 + n];
    int jg = b * NL + j;
    const float* fs = frames + (size_t)pid * 12;
    const float* fj = frames + (size_t)jg * 12;
    float4 A0 = *(const float4*)(fs);
    float4 A2 = *(const float4*)(fs + 8);
    float4 B0 = *(const float4*)(fj);
    float4 B2 = *(const float4*)(fj + 8);
    float dx = B0.x - A0.x, dy = B0.y - A0.y, dzc = B0.z - A0.z;
    float a2x = A2.y, a2y = A2.z, a2z = A2.w;  // z_i
    float zjx = B2.y, zjy = B2.z, zjz = B2.w;
    float dd = dx * dx + dy * dy + dzc * dzc + 1e-12f;
    float dist = sqrtf(dd);
    float zz = a2x * zjx + a2y * zjy + a2z * zjz;
    float dzv = (dx * zjx + dy * zjy + dzc * zjz) / dist;
    float zdv = (a2x * dx + a2y * dy + a2z * dzc) / dist;
    float si = (float)aaidx[pid];
    float sj = (float)aaidx[jg];
    float idist = fminf(fabsf(sj - si), 8.0f);
    float* cr = sCoord + pt * 160 + n * 5;
    cr[0] = dist; cr[1] = zz; cr[2] = dzv; cr[3] = zdv; cr[4] = idist;
    hv = *(const float4*)(head8 + (size_t)jg * 8);  // catt, nf0, nf1
    betaS = head8[(size_t)pid * 8 + 4];
    sattS = head8[(size_t)pid * 8 + 5];
  }
  __syncthreads();
  {
    const int g = lane & 31, nh = lane >> 5;
    float pr[5][5], cn[5];
#pragma unroll
    for (int d = 0; d < 5; d++) {
      cn[d] = sCen[d * 32 + g];
#pragma unroll
      for (int kk = 0; kk < 5; kk++) pr[d][kk] = sPrec[(d * 5 + kk) * 32 + g];
    }
#pragma unroll
    for (int i = 0; i < 16; i++) {
      int n = nh * 16 + i;
      const float* cr = sCoord + pt * 160 + n * 5;
      float df[5];
#pragma unroll
      for (int d = 0; d < 5; d++) df[d] = cr[d] - cn[d];
      float s = 0.0f;
#pragma unroll
      for (int kk = 0; kk < 5; kk++) {
        float y = 0.0f;
#pragma unroll
        for (int d = 0; d < 5; d++) y = fmaf(df[d], pr[d][kk], y);
        s = fmaf(y, y, s);
      }
      sG2[pt * 1056 + n * 33 + g] = __expf(-0.5f * s);
    }
  }
  __syncthreads();
  if (lane < 32) {
    int n = lane;
    float gw = emb2B[0];
#pragma unroll 8
    for (int g = 0; g < 32; g++) gw = fmaf(sG2[pt * 1056 + n * 33 + g], sW2[g], gw);
    gw = fmaxf(gw, 0.0f);
    float e = (n == 0) ? sattS : hv.x;
    float logit = betaS * e;
    float m = logit;
#pragma unroll
    for (int d = 1; d < 32; d <<= 1) m = fmaxf(m, __shfl_xor(m, d, 64));
    float wv = gw * __expf(logit - m);
    float S = wv;
#pragma unroll
    for (int d = 1; d < 32; d <<= 1) S += __shfl_xor(S, d, 64);
    float a = wv / (S + 1e-6f);
    float o0 = a * hv.y, o1 = a * hv.z;
#pragma unroll
    for (int d = 1; d < 32; d <<= 1) {
      o0 += __shfl_xor(o0, d, 64);
      o1 += __shfl_xor(o1, d, 64);
    }
    if (n == 0) {
      out[pid * 2 + 0] = o0;
      out[pid * 2 + 1] = o1;
    }
  }
}

// ---------------------------------------------------------------------------
extern "C" void kernel_launch(void* const* d_in, const int* in_sizes, int n_in,
                              void* d_out, int out_size, void* d_ws, size_t ws_size,
                              hipStream_t stream) {
  const float* attrs = (const float*)d_in[0];
  const float* frames = (const float*)d_in[1];
  const int* aaidx = (const int*)d_in[2];
  const float* cen1 = (const float*)d_in[3];
  const float* prec1 = (const float*)d_in[4];
  const float* opW = (const float*)d_in[5];
  const float* opB = (const float*)d_in[6];
  const float* embW = (const float*)d_in[7];
  const float* embB = (const float*)d_in[8];
  const float* betaW = (const float*)d_in[9];
  const float* betaB = (const float*)d_in[10];
  const float* sattW = (const float*)d_in[11];
  const float* sattB = (const float*)d_in[12];
  const float* cattW = (const float*)d_in[13];
  const float* cattB = (const float*)d_in[14];
  const float* nodW = (const float*)d_in[15];
  const float* nodB = (const float*)d_in[16];
  const float* cen2 = (const float*)d_in[17];
  const float* prec2 = (const float*)d_in[18];
  const float* emb2W = (const float*)d_in[19];
  const float* emb2B = (const float*)d_in[20];
  float* out = (float*)d_out;

  char* ws = (char*)d_ws;
  int* idx32 = (int*)ws;                                   // 16384*32*4  = 2 MiB
  float* outer = (float*)(ws + 2097152);                   // 16384*640*4 = 40 MiB
  float* head8 = (float*)(ws + 2097152 + 41943040);        // 16384*8*4   = 512 KiB

  knn_kernel<<<dim3(2048), dim3(512), 0, stream>>>(frames, idx32);
  stage1_kernel<<<dim3(4096), dim3(256), 0, stream>>>(frames, attrs, aaidx, cen1,
                                                      prec1, idx32, outer);
  gemm_kernel<<<dim3(256), dim3(256), 0, stream>>>(outer, opW, opB, embW, embB,
                                                   betaW, betaB, sattW, sattB,
                                                   cattW, cattB, nodW, nodB, head8);
  stage2_kernel<<<dim3(4096), dim3(256), 0, stream>>>(frames, aaidx, cen2, prec2,
                                                      emb2W, emb2B, idx32, head8, out);
}

// Round 3
// 194.344 us; speedup vs baseline: 2.1162x; 1.2509x over previous
//
#include <hip/hip_runtime.h>

typedef unsigned int u32;
typedef unsigned long long u64;
typedef unsigned short u16;

#define NL 2048

typedef __attribute__((ext_vector_type(8))) short bf16x8;
typedef __attribute__((ext_vector_type(16))) float f32x16;

__device__ __forceinline__ u16 to_bf16(float f) {
  u32 b = __float_as_uint(f);
  b += 0x7FFFu + ((b >> 16) & 1u);
  return (u16)(b >> 16);
}

__device__ __forceinline__ void gload_lds16(const void* g, void* l) {
  __builtin_amdgcn_global_load_lds(
      (const __attribute__((address_space(1))) u32*)g,
      (__attribute__((address_space(3))) u32*)l, 16, 0, 0);
}

__device__ __forceinline__ u64 shfl_xor64(u64 v, int m) {
  int lo = __shfl_xor((int)(u32)v, m, 64);
  int hi = __shfl_xor((int)(u32)(v >> 32), m, 64);
  return ((u64)(u32)hi << 32) | (u32)lo;
}

// full ascending bitonic sort of 64 u32 across the wave (1 per lane)
__device__ __forceinline__ u32 sort64_u32(u32 v, int lane) {
#pragma unroll
  for (int k = 2; k <= 64; k <<= 1) {
#pragma unroll
    for (int j = k >> 1; j > 0; j >>= 1) {
      u32 p = (u32)__shfl_xor((int)v, j, 64);
      bool lower = ((lane & j) == 0);
      bool asc = ((lane & k) == 0);
      u32 lo = v < p ? v : p;
      u32 hi = v < p ? p : v;
      v = (lower == asc) ? lo : hi;
    }
  }
  return v;
}

// full ascending bitonic sort of 128 u64 across the wave (2 per lane)
__device__ __forceinline__ void sort128_u64(u64& f0, u64& f1, int lane) {
  for (int k = 2; k <= 128; k <<= 1) {
    for (int j = k >> 1; j > 0; j >>= 1) {
      if (j == 64) {
        u64 lo = f0 < f1 ? f0 : f1;
        u64 hi = f0 < f1 ? f1 : f0;
        f0 = lo;
        f1 = hi;
      } else {
        bool lower = ((lane & j) == 0);
        bool asc0 = ((lane & k) == 0);
        bool asc1 = (((lane + 64) & k) == 0);
        u64 p0 = shfl_xor64(f0, j);
        u64 p1 = shfl_xor64(f1, j);
        f0 = ((f0 < p0) == (lower == asc0)) ? f0 : p0;
        f1 = ((f1 < p1) == (lower == asc1)) ? f1 : p1;
      }
    }
  }
}

// ---------------------------------------------------------------------------
// Kernel P: prep — transpose/convert weights once per launch.
// blocks 0..159: opWt[o][k] bf16 (128x640); 160..175: embWt[j][k] bf16
// (32x128); 176: w5 (32x8 packed head weights) + b5 (biases).
// ---------------------------------------------------------------------------
__global__ __launch_bounds__(256) void prep_kernel(
    const float* __restrict__ opW, const float* __restrict__ embW,
    const float* __restrict__ betaW, const float* __restrict__ sattW,
    const float* __restrict__ cattW, const float* __restrict__ nodW,
    const float* __restrict__ betaB, const float* __restrict__ sattB,
    const float* __restrict__ cattB, const float* __restrict__ nodB,
    u16* __restrict__ opWt, u16* __restrict__ embWt, float* __restrict__ w5,
    float* __restrict__ b5) {
  const int bx = blockIdx.x, t = threadIdx.x;
  if (bx < 160) {
    int flat = bx * 256 + t;  // 0..40959, 2 k-elems each
    int o = flat / 320;
    int r = flat - o * 320;
    int kk = r * 2;
    float f0 = opW[(size_t)kk * 128 + o];
    float f1 = opW[(size_t)(kk + 1) * 128 + o];
    ((u32*)opWt)[o * 320 + r] = (u32)to_bf16(f0) | ((u32)to_bf16(f1) << 16);
  } else if (bx < 176) {
    int flat = (bx - 160) * 256 + t;  // 0..4095
    int j = flat >> 7, k = flat & 127;
    embWt[j * 128 + k] = to_bf16(embW[(size_t)k * 32 + j]);
  } else {
    if (t < 160) {
      int h = t >> 5, j = t & 31;
      float v = (h == 0) ? betaW[j]
                : (h == 1) ? sattW[j]
                : (h == 2) ? cattW[j]
                : (h == 3) ? nodW[j * 2]
                           : nodW[j * 2 + 1];
      w5[j * 8 + h] = v;
    } else if (t < 165) {
      int h = t - 160;
      float v = (h == 0) ? betaB[0]
                : (h == 1) ? sattB[0]
                : (h == 2) ? cattB[0]
                : (h == 3) ? nodB[0]
                           : nodB[1];
      b5[h] = v;
    }
  }
}

// ---------------------------------------------------------------------------
// Kernel A: exact 32-NN (unchanged from round 2 — validated)
// ---------------------------------------------------------------------------
__global__ __launch_bounds__(512) void knn_kernel(const float* __restrict__ frames,
                                                  int* __restrict__ idx32) {
  __shared__ float4 cand[2048];
  __shared__ u64 comp[8][256];
  const int tid = threadIdx.x;
  const int w = tid >> 6, lane = tid & 63;
  const int query = blockIdx.x * 8 + w;
  const int b = query >> 11, lq = query & (NL - 1);

#pragma unroll
  for (int i = 0; i < 4; i++) {
    int l = tid + i * 512;
    const float* fp = frames + (size_t)(b * NL + l) * 12;
    float4 fr = *(const float4*)fp;
    cand[l] = make_float4(fr.x, fr.y, fr.z,
                          fr.x * fr.x + fr.y * fr.y + fr.z * fr.z);
  }
  __syncthreads();

  float4 me = cand[lq];
  u32 k[32];
  u32 m = 0xFFFFFFFFu;
#pragma unroll
  for (int i = 0; i < 32; i++) {
    float4 c = cand[i * 64 + lane];
    float dot = c.x * me.x + c.y * me.y + c.z * me.z;
    float d2 = (me.w + c.w) - 2.0f * dot;
    u32 kb = __float_as_uint(d2);
    u32 key = kb ^ ((u32)((int)kb >> 31) | 0x80000000u);
    k[i] = key;
    m = key < m ? key : m;
  }

  u32 ms = sort64_u32(m, lane);
  u32 T0 = (u32)__shfl((int)ms, 31, 64);

  int base = 0;
#pragma unroll
  for (int i = 0; i < 32; i++) {
    bool flag = (k[i] <= T0);
    u64 mask = __ballot(flag);
    if (flag) {
      u32 rank = __builtin_amdgcn_mbcnt_hi(
          (u32)(mask >> 32), __builtin_amdgcn_mbcnt_lo((u32)mask, 0u));
      int pos = base + (int)rank;
      if (pos < 256) comp[w][pos] = ((u64)k[i] << 32) | (u32)(i * 64 + lane);
    }
    base += (int)__popcll(mask);
  }
  int cnt = base < 256 ? base : 256;
  __syncthreads();

  u64 f0 = ~0ull;
  for (int c = 0; c * 64 < cnt; c++) {
    int p = c * 64 + lane;
    u64 f1 = (p < cnt) ? comp[w][p] : ~0ull;
    sort128_u64(f0, f1, lane);
    f0 = (lane < 32) ? f0 : ~0ull;
  }
  if (lane < 32)
    idx32[(size_t)query * 32 + lane] = (int)(f0 & 0xFFFFFFFFull);
}

// ---------------------------------------------------------------------------
// Kernel B: stage-1 coords + gaussians + outer product -> bf16 outer[p][640]
// block = 256 (4 points x 64 lanes), grid = 4096.
// Outer phase is g-major: lane owns gaussian g (+h group), reads sG1T/sAttrT
// with ~56 LDS instrs/thread (was 320 scalar reads).
// ---------------------------------------------------------------------------
__global__ __launch_bounds__(256) void stage1_kernel(
    const float* __restrict__ frames, const float* __restrict__ attrs,
    const int* __restrict__ aaidx, const float* __restrict__ cen1,
    const float* __restrict__ prec1, const int* __restrict__ idx32,
    u16* __restrict__ outer) {
  __shared__ float sPrec[1568];
  __shared__ float sCen[224];
  __shared__ float sCoord[4 * 16 * 8];
  __shared__ float sAttrT[4 * 20 * 16];  // [pt][h][n]
  __shared__ float sG1T[4 * 32 * 17];    // [pt][g][n], pitch 17
  const int tid = threadIdx.x;
  for (int i = tid; i < 1568; i += 256) sPrec[i] = prec1[i];
  if (tid < 224) sCen[tid] = cen1[tid];
  const int pt = tid >> 6, lane = tid & 63;
  const int pid = blockIdx.x * 4 + pt;
  const int b = pid >> 11;
  __syncthreads();

  if (lane < 16) {
    int n = lane;
    int j = idx32[pid * 32 + n];
    int jg = b * NL + j;
    const float* fs = frames + (size_t)pid * 12;
    const float* fj = frames + (size_t)jg * 12;
    float4 A0 = *(const float4*)(fs);
    float4 A1 = *(const float4*)(fs + 4);
    float4 A2 = *(const float4*)(fs + 8);
    float4 B0 = *(const float4*)(fj);
    float4 B2 = *(const float4*)(fj + 8);
    float dx = B0.x - A0.x, dy = B0.y - A0.y, dzc = B0.z - A0.z;
    float a0x = A0.w, a0y = A1.x, a0z = A1.y;
    float a1x = A1.z, a1y = A1.w, a1z = A2.x;
    float a2x = A2.y, a2y = A2.z, a2z = A2.w;  // z_i == axes[2]
    float zjx = B2.y, zjy = B2.z, zjz = B2.w;
    float dd = dx * dx + dy * dy + dzc * dzc + 1e-12f;
    float dist = sqrtf(dd);
    float e0 = dx * a0x + dy * a0y + dzc * a0z;
    float e1 = dx * a1x + dy * a1y + dzc * a1z;
    float e2 = dx * a2x + dy * a2y + dzc * a2z;
    float zz = a2x * zjx + a2y * zjy + a2z * zjz;
    float dzv = (dx * zjx + dy * zjy + dzc * zjz) / dist;
    float zdv = (a2x * dx + a2y * dy + a2z * dzc) / dist;
    float si = (float)aaidx[pid];
    float sj = (float)aaidx[jg];
    float idist = fminf(fabsf(sj - si), 8.0f);
    float* cr = sCoord + pt * 128 + n * 8;
    cr[0] = e0; cr[1] = e1; cr[2] = e2; cr[3] = idist;
    cr[4] = zz; cr[5] = dzv; cr[6] = zdv;
    const float* ar = attrs + (size_t)jg * 20;
    float4 q0 = *(const float4*)(ar);
    float4 q1 = *(const float4*)(ar + 4);
    float4 q2 = *(const float4*)(ar + 8);
    float4 q3 = *(const float4*)(ar + 12);
    float4 q4 = *(const float4*)(ar + 16);
    float av[20] = {q0.x, q0.y, q0.z, q0.w, q1.x, q1.y, q1.z, q1.w,
                    q2.x, q2.y, q2.z, q2.w, q3.x, q3.y, q3.z, q3.w,
                    q4.x, q4.y, q4.z, q4.w};
#pragma unroll
    for (int h = 0; h < 20; h++) sAttrT[pt * 320 + h * 16 + n] = av[h];
  }
  __syncthreads();
  {
    const int g = lane & 31, nh = lane >> 5;
    float pr[7][7], cn[7];
#pragma unroll
    for (int d = 0; d < 7; d++) {
      cn[d] = sCen[d * 32 + g];
#pragma unroll
      for (int kk = 0; kk < 7; kk++) pr[d][kk] = sPrec[(d * 7 + kk) * 32 + g];
    }
#pragma unroll
    for (int i = 0; i < 8; i++) {
      int n = nh * 8 + i;
      const float* cr = sCoord + pt * 128 + n * 8;
      float df[7];
#pragma unroll
      for (int d = 0; d < 7; d++) df[d] = cr[d] - cn[d];
      float s = 0.0f;
#pragma unroll
      for (int kk = 0; kk < 7; kk++) {
        float y = 0.0f;
#pragma unroll
        for (int d = 0; d < 7; d++) y = fmaf(df[d], pr[d][kk], y);
        s = fmaf(y, y, s);
      }
      sG1T[pt * 544 + g * 17 + n] = __expf(-0.5f * s);
    }
  }
  __syncthreads();
  {
    const int g = lane & 31, hg = lane >> 5;
    float g16[16];
#pragma unroll
    for (int n = 0; n < 16; n++) g16[n] = sG1T[pt * 544 + g * 17 + n];
    u32* orow = (u32*)(outer + (size_t)pid * 640) + (g * 20 + hg * 10) / 2;
#pragma unroll
    for (int i = 0; i < 5; i++) {
      int h0 = hg * 10 + i * 2, h1 = h0 + 1;
      float a0 = 0.f, a1 = 0.f;
#pragma unroll
      for (int c = 0; c < 4; c++) {
        float4 v0 = *(float4*)&sAttrT[pt * 320 + h0 * 16 + c * 4];
        float4 v1 = *(float4*)&sAttrT[pt * 320 + h1 * 16 + c * 4];
        a0 = fmaf(v0.x, g16[c * 4 + 0], a0);
        a0 = fmaf(v0.y, g16[c * 4 + 1], a0);
        a0 = fmaf(v0.z, g16[c * 4 + 2], a0);
        a0 = fmaf(v0.w, g16[c * 4 + 3], a0);
        a1 = fmaf(v1.x, g16[c * 4 + 0], a1);
        a1 = fmaf(v1.y, g16[c * 4 + 1], a1);
        a1 = fmaf(v1.z, g16[c * 4 + 2], a1);
        a1 = fmaf(v1.w, g16[c * 4 + 3], a1);
      }
      orow[i] = (u32)to_bf16(a0) | ((u32)to_bf16(a1) << 16);
    }
  }
}

// ---------------------------------------------------------------------------
// Kernel C: bf16 MFMA GEMM (16384x640 @ 640x128) + fused emb MFMA + heads.
// grid = 512 (tile 32 points x 128 outs), block = 256 (4 waves, one 32x32
// tile each). A/B staged with XOR-swizzled global_load_lds width=16
// (swizzle g^=row&7 -> conflict-free ds_read_b128 frag reads).
// head8 layout per point: [catt, nf0, nf1, -, beta, satt, -, -]
// ---------------------------------------------------------------------------
__global__ __launch_bounds__(256) void gemm_kernel(
    const u16* __restrict__ outer,  // [16384][640] bf16
    const u16* __restrict__ opWt,   // [128][640] bf16 (o-major)
    const float* __restrict__ opB,
    const u16* __restrict__ embWt,  // [32][128] bf16 (j-major)
    const float* __restrict__ embB,
    const float* __restrict__ w5,   // [32][8] packed head weights
    const float* __restrict__ b5,   // [8] head biases
    float* __restrict__ head8) {
  __shared__ char smem[32768];
  const int tid = threadIdx.x;
  const int w = tid >> 6, lane = tid & 63;
  const int p0 = blockIdx.x * 32;
  const int lr = lane >> 3, lc = lane & 7;
  const int gsw = lc ^ lr;  // swizzled fetch group for staging
  const int m = lane & 31, kh = lane >> 5;

  f32x16 acc;
#pragma unroll
  for (int r = 0; r < 16; r++) acc[r] = 0.f;

  const u16* gA = outer + (size_t)(p0 + w * 8 + lr) * 640 + gsw * 8;

  for (int cc = 0; cc < 10; cc++) {
    // stage A: 32 rows x 64 bf16, wave w -> rows w*8..w*8+8
    gload_lds16(gA + cc * 64, smem + w * 1024);
    // stage B: 128 rows x 64 bf16, wave w -> rows w*32..w*32+32
#pragma unroll
    for (int i = 0; i < 4; i++) {
      const u16* gB = opWt + (size_t)(w * 32 + i * 8 + lr) * 640 + cc * 64 + gsw * 8;
      gload_lds16(gB, smem + 4096 + w * 4096 + i * 1024);
    }
    __syncthreads();
#pragma unroll
    for (int s = 0; s < 4; s++) {
      int pg = (s * 2 + kh) ^ (m & 7);
      bf16x8 av = *(bf16x8*)(smem + m * 128 + pg * 16);
      bf16x8 bv = *(bf16x8*)(smem + 4096 + w * 4096 + m * 128 + pg * 16);
      acc = __builtin_amdgcn_mfma_f32_32x32x16_bf16(av, bv, acc, 0, 0, 0);
    }
    __syncthreads();
  }

  // ---- epilogue: bias+relu -> bf16 fTile (smem 0..8192, swizzled) ----
  const int o = w * 32 + m;
  float bo = opB[o];
  // stage embWt (32 rows x 128 bf16 = 8KB) into smem+8192, swizzled
#pragma unroll
  for (int i = 0; i < 2; i++) {
    int j = w * 8 + i * 4 + (lane >> 4);
    int ge = (lane & 15) ^ (j & 7);
    gload_lds16(embWt + j * 128 + ge * 8, smem + 8192 + w * 2048 + i * 1024);
  }
  u16* sFb = (u16*)smem;
#pragma unroll
  for (int r = 0; r < 16; r++) {
    int mm = (r & 3) + 8 * (r >> 2) + 4 * kh;
    float v = fmaxf(acc[r] + bo, 0.f);
    int pg = (o >> 3) ^ (mm & 7);
    sFb[mm * 128 + pg * 8 + (o & 7)] = to_bf16(v);
  }
  __syncthreads();

  // ---- emb MFMA: D2[p][j] = fTile(32x128) @ embWt^T(128x32), k split over
  // waves (wave w -> ksteps 2w, 2w+1), partials reduced via LDS ----
  f32x16 acc2;
#pragma unroll
  for (int r = 0; r < 16; r++) acc2[r] = 0.f;
#pragma unroll
  for (int t2 = 0; t2 < 2; t2++) {
    int gg = (w * 2 + t2) * 2 + kh;  // 16B group 0..15
    int pg = gg ^ (m & 7);
    bf16x8 av = *(bf16x8*)(smem + m * 256 + pg * 16);
    bf16x8 bv = *(bf16x8*)(smem + 8192 + m * 256 + pg * 16);
    acc2 = __builtin_amdgcn_mfma_f32_32x32x16_bf16(av, bv, acc2, 0, 0, 0);
  }
  float* scr = (float*)(smem + 16384) + w * 1024;
#pragma unroll
  for (int r = 0; r < 16; r++) {
    int mm = (r & 3) + 8 * (r >> 2) + 4 * kh;
    scr[mm * 32 + m] = acc2[r];
  }
  __syncthreads();

  // reduce 4 partials + bias + relu -> sE[p][36]
  {
    float* sc = (float*)(smem + 16384);
    int i4 = tid * 4;
    float4 v0 = *(float4*)(sc + i4);
    float4 v1 = *(float4*)(sc + 1024 + i4);
    float4 v2 = *(float4*)(sc + 2048 + i4);
    float4 v3 = *(float4*)(sc + 3072 + i4);
    int pp = tid >> 3, j0 = (tid & 7) * 4;
    float4 eb = *(const float4*)(embB + j0);
    float4 e;
    e.x = fmaxf(v0.x + v1.x + v2.x + v3.x + eb.x, 0.f);
    e.y = fmaxf(v0.y + v1.y + v2.y + v3.y + eb.y, 0.f);
    e.z = fmaxf(v0.z + v1.z + v2.z + v3.z + eb.z, 0.f);
    e.w = fmaxf(v0.w + v1.w + v2.w + v3.w + eb.w, 0.f);
    *(float4*)((float*)smem + pp * 36 + j0) = e;
  }
  __syncthreads();

  // heads: 5 heads x 32 points
  if (tid < 160) {
    int h = tid >> 5, p = tid & 31;
    const float* sE = (const float*)smem + p * 36;
    float a = b5[h];
#pragma unroll
    for (int j = 0; j < 32; j++) a = fmaf(sE[j], w5[j * 8 + h], a);
    a = fmaxf(a, 0.f);
    int slot = (h < 2) ? (h + 4) : (h - 2);  // beta->4 satt->5 catt->0 nf0->1 nf1->2
    head8[(size_t)(p0 + p) * 8 + slot] = a;
  }
}

// ---------------------------------------------------------------------------
// Kernel E: stage-2 (unchanged from round 2 — validated)
// ---------------------------------------------------------------------------
__global__ __launch_bounds__(256) void stage2_kernel(
    const float* __restrict__ frames, const int* __restrict__ aaidx,
    const float* __restrict__ cen2, const float* __restrict__ prec2,
    const float* __restrict__ emb2W, const float* __restrict__ emb2B,
    const int* __restrict__ idx32, const float* __restrict__ head8,
    float* __restrict__ out) {
  __shared__ float sPrec[800];
  __shared__ float sCen[160];
  __shared__ float sW2[32];
  __shared__ float sCoord[4 * 32 * 5];
  __shared__ float sG2[4 * 32 * 33];
  const int tid = threadIdx.x;
  for (int i = tid; i < 800; i += 256) sPrec[i] = prec2[i];
  if (tid < 160) sCen[tid] = cen2[tid];
  if (tid < 32) sW2[tid] = emb2W[tid];
  const int pt = tid >> 6, lane = tid & 63;
  const int pid = blockIdx.x * 4 + pt;
  const int b = pid >> 11;
  __syncthreads();

  float4 hv = make_float4(0.f, 0.f, 0.f, 0.f);
  float betaS = 0.f, sattS = 0.f;
  if (lane < 32) {
    int n = lane;
    int j = idx32[pid * 32 + n];
    int jg = b * NL + j;
    const float* fs = frames + (size_t)pid * 12;
    const float* fj = frames + (size_t)jg * 12;
    float4 A0 = *(const float4*)(fs);
    float4 A2 = *(const float4*)(fs + 8);
    float4 B0 = *(const float4*)(fj);
    float4 B2 = *(const float4*)(fj + 8);
    float dx = B0.x - A0.x, dy = B0.y - A0.y, dzc = B0.z - A0.z;
    float a2x = A2.y, a2y = A2.z, a2z = A2.w;  // z_i
    float zjx = B2.y, zjy = B2.z, zjz = B2.w;
    float dd = dx * dx + dy * dy + dzc * dzc + 1e-12f;
    float dist = sqrtf(dd);
    float zz = a2x * zjx + a2y * zjy + a2z * zjz;
    float dzv = (dx * zjx + dy * zjy + dzc * zjz) / dist;
    float zdv = (a2x * dx + a2y * dy + a2z * dzc) / dist;
    float si = (float)aaidx[pid];
    float sj = (float)aaidx[jg];
    float idist = fminf(fabsf(sj - si), 8.0f);
    float* cr = sCoord + pt * 160 + n * 5;
    cr[0] = dist; cr[1] = zz; cr[2] = dzv; cr[3] = zdv; cr[4] = idist;
    hv = *(const float4*)(head8 + (size_t)jg * 8);  // catt, nf0, nf1
    betaS = head8[(size_t)pid * 8 + 4];
    sattS = head8[(size_t)pid * 8 + 5];
  }
  __syncthreads();
  {
    const int g = lane & 31, nh = lane >> 5;
    float pr[5][5], cn[5];
#pragma unroll
    for (int d = 0; d < 5; d++) {
      cn[d] = sCen[d * 32 + g];
#pragma unroll
      for (int kk = 0; kk < 5; kk++) pr[d][kk] = sPrec[(d * 5 + kk) * 32 + g];
    }
#pragma unroll
    for (int i = 0; i < 16; i++) {
      int n = nh * 16 + i;
      const float* cr = sCoord + pt * 160 + n * 5;
      float df[5];
#pragma unroll
      for (int d = 0; d < 5; d++) df[d] = cr[d] - cn[d];
      float s = 0.0f;
#pragma unroll
      for (int kk = 0; kk < 5; kk++) {
        float y = 0.0f;
#pragma unroll
        for (int d = 0; d < 5; d++) y = fmaf(df[d], pr[d][kk], y);
        s = fmaf(y, y, s);
      }
      sG2[pt * 1056 + n * 33 + g] = __expf(-0.5f * s);
    }
  }
  __syncthreads();
  if (lane < 32) {
    int n = lane;
    float gw = emb2B[0];
#pragma unroll 8
    for (int g = 0; g < 32; g++) gw = fmaf(sG2[pt * 1056 + n * 33 + g], sW2[g], gw);
    gw = fmaxf(gw, 0.0f);
    float e = (n == 0) ? sattS : hv.x;
    float logit = betaS * e;
    float mx = logit;
#pragma unroll
    for (int d = 1; d < 32; d <<= 1) mx = fmaxf(mx, __shfl_xor(mx, d, 64));
    float wv = gw * __expf(logit - mx);
    float S = wv;
#pragma unroll
    for (int d = 1; d < 32; d <<= 1) S += __shfl_xor(S, d, 64);
    float a = wv / (S + 1e-6f);
    float o0 = a * hv.y, o1 = a * hv.z;
#pragma unroll
    for (int d = 1; d < 32; d <<= 1) {
      o0 += __shfl_xor(o0, d, 64);
      o1 += __shfl_xor(o1, d, 64);
    }
    if (n == 0) {
      out[pid * 2 + 0] = o0;
      out[pid * 2 + 1] = o1;
    }
  }
}

// ---------------------------------------------------------------------------
extern "C" void kernel_launch(void* const* d_in, const int* in_sizes, int n_in,
                              void* d_out, int out_size, void* d_ws, size_t ws_size,
                              hipStream_t stream) {
  const float* attrs = (const float*)d_in[0];
  const float* frames = (const float*)d_in[1];
  const int* aaidx = (const int*)d_in[2];
  const float* cen1 = (const float*)d_in[3];
  const float* prec1 = (const float*)d_in[4];
  const float* opW = (const float*)d_in[5];
  const float* opB = (const float*)d_in[6];
  const float* embW = (const float*)d_in[7];
  const float* embB = (const float*)d_in[8];
  const float* betaW = (const float*)d_in[9];
  const float* betaB = (const float*)d_in[10];
  const float* sattW = (const float*)d_in[11];
  const float* sattB = (const float*)d_in[12];
  const float* cattW = (const float*)d_in[13];
  const float* cattB = (const float*)d_in[14];
  const float* nodW = (const float*)d_in[15];
  const float* nodB = (const float*)d_in[16];
  const float* cen2 = (const float*)d_in[17];
  const float* prec2 = (const float*)d_in[18];
  const float* emb2W = (const float*)d_in[19];
  const float* emb2B = (const float*)d_in[20];
  float* out = (float*)d_out;

  char* ws = (char*)d_ws;
  int* idx32 = (int*)ws;                              // 2 MiB
  u16* outer_bf = (u16*)(ws + 2097152);               // 16384*640*2 = 20 MiB
  float* head8 = (float*)(ws + 23068672);             // 512 KiB
  u16* opWt = (u16*)(ws + 23592960);                  // 160 KiB
  u16* embWt = (u16*)(ws + 23756800);                 // 8 KiB
  float* w5 = (float*)(ws + 23764992);                // 1 KiB
  float* b5 = (float*)(ws + 23766016);                // 32 B

  prep_kernel<<<dim3(177), dim3(256), 0, stream>>>(
      opW, embW, betaW, sattW, cattW, nodW, betaB, sattB, cattB, nodB, opWt,
      embWt, w5, b5);
  knn_kernel<<<dim3(2048), dim3(512), 0, stream>>>(frames, idx32);
  stage1_kernel<<<dim3(4096), dim3(256), 0, stream>>>(frames, attrs, aaidx, cen1,
                                                      prec1, idx32, outer_bf);
  gemm_kernel<<<dim3(512), dim3(256), 0, stream>>>(outer_bf, opWt, opB, embWt,
                                                   embB, w5, b5, head8);
  stage2_kernel<<<dim3(4096), dim3(256), 0, stream>>>(frames, aaidx, cen2, prec2,
                                                      emb2W, emb2B, idx32, head8, out);
}

// Round 4
// 182.751 us; speedup vs baseline: 2.2504x; 1.0634x over previous
//
#include <hip/hip_runtime.h>

typedef unsigned int u32;
typedef unsigned long long u64;
typedef unsigned short u16;

#define NL 2048

typedef __attribute__((ext_vector_type(8))) short bf16x8;
typedef __attribute__((ext_vector_type(16))) float f32x16;

__device__ __forceinline__ u16 to_bf16(float f) {
  u32 b = __float_as_uint(f);
  b += 0x7FFFu + ((b >> 16) & 1u);
  return (u16)(b >> 16);
}

__device__ __forceinline__ void gload_lds16(const void* g, void* l) {
  __builtin_amdgcn_global_load_lds(
      (const __attribute__((address_space(1))) u32*)g,
      (__attribute__((address_space(3))) u32*)l, 16, 0, 0);
}

// full ascending bitonic sort of 64 u32 across the wave (1 per lane)
__device__ __forceinline__ u32 sort64_u32(u32 v, int lane) {
#pragma unroll
  for (int k = 2; k <= 64; k <<= 1) {
#pragma unroll
    for (int j = k >> 1; j > 0; j >>= 1) {
      u32 p = (u32)__shfl_xor((int)v, j, 64);
      bool lower = ((lane & j) == 0);
      bool asc = ((lane & k) == 0);
      u32 lo = v < p ? v : p;
      u32 hi = v < p ? p : v;
      v = (lower == asc) ? lo : hi;
    }
  }
  return v;
}

// ---------------------------------------------------------------------------
// Kernel A+P: exact 32-NN (rank-select) + weight prep folded in.
// grid = 2059 x 512 threads:
//   bx <  2048 : knn, one wave per query (8 queries/block)
//   bx 2048-2057: opW transpose tile (64 k-rows x 128 o) -> opWt bf16
//   bx == 2058 : embW transpose + w5/b5 packing
// knn: threshold T0 = 32nd smallest of 64 lane-minima; compact keys<=T0
// (E[cnt]~44); exact rank via broadcast count; scatter idx to rank<32.
// ---------------------------------------------------------------------------
__global__ __launch_bounds__(512) void knn_prep_kernel(
    const float* __restrict__ frames, int* __restrict__ idx32,
    const float* __restrict__ opW, const float* __restrict__ embW,
    const float* __restrict__ betaW, const float* __restrict__ sattW,
    const float* __restrict__ cattW, const float* __restrict__ nodW,
    const float* __restrict__ betaB, const float* __restrict__ sattB,
    const float* __restrict__ cattB, const float* __restrict__ nodB,
    u16* __restrict__ opWt, u16* __restrict__ embWt, float* __restrict__ w5,
    float* __restrict__ b5) {
  __shared__ union U {
    struct {
      float4 cand[2048];
      u64 comp[8][256];
    } k;
    float tp[128 * 73];
  } sm;
  const int bx = blockIdx.x;
  const int tid = threadIdx.x;

  if (bx >= 2048) {
    if (bx < 2058) {
      // opW [640][128] fp32 -> opWt [128][640] bf16, tile k0..k0+64
      const int k0 = (bx - 2048) * 64;
#pragma unroll
      for (int j = 0; j < 4; j++) {
        int f = tid + j * 512;
        int kk = f >> 5;
        int o4 = (f & 31) * 4;
        float4 v = *(const float4*)(opW + (size_t)(k0 + kk) * 128 + o4);
        sm.tp[(o4 + 0) * 73 + kk] = v.x;
        sm.tp[(o4 + 1) * 73 + kk] = v.y;
        sm.tp[(o4 + 2) * 73 + kk] = v.z;
        sm.tp[(o4 + 3) * 73 + kk] = v.w;
      }
      __syncthreads();
      u32* ow = (u32*)opWt;
#pragma unroll
      for (int j = 0; j < 8; j++) {
        int f = tid + j * 512;
        int o = f >> 5, q = f & 31;
        float lo = sm.tp[o * 73 + q * 2];
        float hi = sm.tp[o * 73 + q * 2 + 1];
        ow[o * 320 + (k0 >> 1) + q] = (u32)to_bf16(lo) | ((u32)to_bf16(hi) << 16);
      }
    } else {
      for (int f = tid; f < 4096; f += 512) {
        int j = f >> 7, kk = f & 127;
        embWt[f] = to_bf16(embW[(size_t)kk * 32 + j]);
      }
      if (tid < 160) {
        int h = tid >> 5, j = tid & 31;
        float v = (h == 0) ? betaW[j]
                  : (h == 1) ? sattW[j]
                  : (h == 2) ? cattW[j]
                  : (h == 3) ? nodW[j * 2]
                             : nodW[j * 2 + 1];
        w5[j * 8 + h] = v;
      } else if (tid < 165) {
        int h = tid - 160;
        float v = (h == 0) ? betaB[0]
                  : (h == 1) ? sattB[0]
                  : (h == 2) ? cattB[0]
                  : (h == 3) ? nodB[0]
                             : nodB[1];
        b5[h] = v;
      }
    }
    return;
  }

  const int w = tid >> 6, lane = tid & 63;
  const int query = bx * 8 + w;
  const int b = query >> 11, lq = query & (NL - 1);

#pragma unroll
  for (int i = 0; i < 4; i++) {
    int l = tid + i * 512;
    const float* fp = frames + (size_t)(b * NL + l) * 12;
    float4 fr = *(const float4*)fp;
    sm.k.cand[l] = make_float4(fr.x, fr.y, fr.z,
                               fr.x * fr.x + fr.y * fr.y + fr.z * fr.z);
  }
  __syncthreads();

  float4 me = sm.k.cand[lq];
  u32 k[32];
  u32 m = 0xFFFFFFFFu;
#pragma unroll
  for (int i = 0; i < 32; i++) {
    float4 c = sm.k.cand[i * 64 + lane];
    float dot = c.x * me.x + c.y * me.y + c.z * me.z;
    float d2 = (me.w + c.w) - 2.0f * dot;
    u32 kb = __float_as_uint(d2);
    u32 key = kb ^ ((u32)((int)kb >> 31) | 0x80000000u);
    k[i] = key;
    m = key < m ? key : m;
  }

  u32 ms = sort64_u32(m, lane);
  u32 T0 = (u32)__shfl((int)ms, 31, 64);

  int base = 0;
#pragma unroll
  for (int i = 0; i < 32; i++) {
    bool flag = (k[i] <= T0);
    u64 mask = __ballot(flag);
    if (flag) {
      u32 rank = __builtin_amdgcn_mbcnt_hi(
          (u32)(mask >> 32), __builtin_amdgcn_mbcnt_lo((u32)mask, 0u));
      int pos = base + (int)rank;
      if (pos < 256) sm.k.comp[w][pos] = ((u64)k[i] << 32) | (u32)(i * 64 + lane);
    }
    base += (int)__popcll(mask);
  }
  int cnt = base < 256 ? base : 256;
  __syncthreads();  // uniform: orders in-wave LDS writes before reads

  // exact rank select: rank(e) = #{entries < e}; scatter idx if rank < 32.
  // (key,idx) u64 keys are unique -> ranks 0..cnt-1 distinct, exactly 32 hit.
  for (int b0 = 0; b0 < cnt; b0 += 64) {
    bool live = (b0 + lane < cnt);
    u64 e = live ? sm.k.comp[w][b0 + lane] : ~0ull;
    int r = 0;
    for (int mi = 0; mi < cnt; mi++) {
      u64 em = sm.k.comp[w][mi];  // broadcast read
      r += (em < e) ? 1 : 0;
    }
    if (live && r < 32)
      idx32[(size_t)query * 32 + r] = (int)(e & 0xFFFFFFFFull);
  }
}

// ---------------------------------------------------------------------------
// Kernel B: stage-1 coords + gaussians + outer product -> bf16 outer[p][640]
// block = 256 (4 points x 64 lanes), grid = 4096.
// Precision/center columns loaded per-lane from global (L1-resident),
// no sPrec staging barrier.
// ---------------------------------------------------------------------------
__global__ __launch_bounds__(256) void stage1_kernel(
    const float* __restrict__ frames, const float* __restrict__ attrs,
    const int* __restrict__ aaidx, const float* __restrict__ cen1,
    const float* __restrict__ prec1, const int* __restrict__ idx32,
    u16* __restrict__ outer) {
  __shared__ float sCoord[4 * 16 * 8];
  __shared__ float sAttrT[4 * 20 * 16];  // [pt][h][n]
  __shared__ float sG1T[4 * 32 * 17];    // [pt][g][n], pitch 17
  const int tid = threadIdx.x;
  const int pt = tid >> 6, lane = tid & 63;
  const int pid = blockIdx.x * 4 + pt;
  const int b = pid >> 11;
  const int g = lane & 31;

  float pr[7][7], cn[7];
#pragma unroll
  for (int d = 0; d < 7; d++) {
    cn[d] = cen1[d * 32 + g];
#pragma unroll
    for (int kk = 0; kk < 7; kk++) pr[d][kk] = prec1[(d * 7 + kk) * 32 + g];
  }

  if (lane < 16) {
    int n = lane;
    int j = idx32[pid * 32 + n];
    int jg = b * NL + j;
    const float* fs = frames + (size_t)pid * 12;
    const float* fj = frames + (size_t)jg * 12;
    float4 A0 = *(const float4*)(fs);
    float4 A1 = *(const float4*)(fs + 4);
    float4 A2 = *(const float4*)(fs + 8);
    float4 B0 = *(const float4*)(fj);
    float4 B2 = *(const float4*)(fj + 8);
    float dx = B0.x - A0.x, dy = B0.y - A0.y, dzc = B0.z - A0.z;
    float a0x = A0.w, a0y = A1.x, a0z = A1.y;
    float a1x = A1.z, a1y = A1.w, a1z = A2.x;
    float a2x = A2.y, a2y = A2.z, a2z = A2.w;  // z_i == axes[2]
    float zjx = B2.y, zjy = B2.z, zjz = B2.w;
    float dd = dx * dx + dy * dy + dzc * dzc + 1e-12f;
    float dist = sqrtf(dd);
    float e0 = dx * a0x + dy * a0y + dzc * a0z;
    float e1 = dx * a1x + dy * a1y + dzc * a1z;
    float e2 = dx * a2x + dy * a2y + dzc * a2z;
    float zz = a2x * zjx + a2y * zjy + a2z * zjz;
    float dzv = (dx * zjx + dy * zjy + dzc * zjz) / dist;
    float zdv = (a2x * dx + a2y * dy + a2z * dzc) / dist;
    float si = (float)aaidx[pid];
    float sj = (float)aaidx[jg];
    float idist = fminf(fabsf(sj - si), 8.0f);
    float* cr = sCoord + pt * 128 + n * 8;
    cr[0] = e0; cr[1] = e1; cr[2] = e2; cr[3] = idist;
    cr[4] = zz; cr[5] = dzv; cr[6] = zdv;
    const float* ar = attrs + (size_t)jg * 20;
    float4 q0 = *(const float4*)(ar);
    float4 q1 = *(const float4*)(ar + 4);
    float4 q2 = *(const float4*)(ar + 8);
    float4 q3 = *(const float4*)(ar + 12);
    float4 q4 = *(const float4*)(ar + 16);
    float av[20] = {q0.x, q0.y, q0.z, q0.w, q1.x, q1.y, q1.z, q1.w,
                    q2.x, q2.y, q2.z, q2.w, q3.x, q3.y, q3.z, q3.w,
                    q4.x, q4.y, q4.z, q4.w};
#pragma unroll
    for (int h = 0; h < 20; h++) sAttrT[pt * 320 + h * 16 + n] = av[h];
  }
  __syncthreads();
  {
    const int nh = lane >> 5;
#pragma unroll
    for (int i = 0; i < 8; i++) {
      int n = nh * 8 + i;
      const float* cr = sCoord + pt * 128 + n * 8;
      float df[7];
#pragma unroll
      for (int d = 0; d < 7; d++) df[d] = cr[d] - cn[d];
      float s = 0.0f;
#pragma unroll
      for (int kk = 0; kk < 7; kk++) {
        float y = 0.0f;
#pragma unroll
        for (int d = 0; d < 7; d++) y = fmaf(df[d], pr[d][kk], y);
        s = fmaf(y, y, s);
      }
      sG1T[pt * 544 + g * 17 + n] = __expf(-0.5f * s);
    }
  }
  __syncthreads();
  {
    const int hg = lane >> 5;
    float g16[16];
#pragma unroll
    for (int n = 0; n < 16; n++) g16[n] = sG1T[pt * 544 + g * 17 + n];
    u32* orow = (u32*)(outer + (size_t)pid * 640) + (g * 20 + hg * 10) / 2;
#pragma unroll
    for (int i = 0; i < 5; i++) {
      int h0 = hg * 10 + i * 2, h1 = h0 + 1;
      float a0 = 0.f, a1 = 0.f;
#pragma unroll
      for (int c = 0; c < 4; c++) {
        float4 v0 = *(float4*)&sAttrT[pt * 320 + h0 * 16 + c * 4];
        float4 v1 = *(float4*)&sAttrT[pt * 320 + h1 * 16 + c * 4];
        a0 = fmaf(v0.x, g16[c * 4 + 0], a0);
        a0 = fmaf(v0.y, g16[c * 4 + 1], a0);
        a0 = fmaf(v0.z, g16[c * 4 + 2], a0);
        a0 = fmaf(v0.w, g16[c * 4 + 3], a0);
        a1 = fmaf(v1.x, g16[c * 4 + 0], a1);
        a1 = fmaf(v1.y, g16[c * 4 + 1], a1);
        a1 = fmaf(v1.z, g16[c * 4 + 2], a1);
        a1 = fmaf(v1.w, g16[c * 4 + 3], a1);
      }
      orow[i] = (u32)to_bf16(a0) | ((u32)to_bf16(a1) << 16);
    }
  }
}

// ---------------------------------------------------------------------------
// Kernel C: bf16 MFMA GEMM, full-K single-barrier variant.
// grid = 512 (tile 32 points x 128 outs), block = 256 (4 waves, one 32x32
// tile each). A (32x640) fully staged via swizzled global_load_lds in 10
// round-3-layout chunks, ONE barrier, then 40 MFMAs with B-frags read
// directly from L2-resident opWt. Epilogue identical to validated round 3.
// ---------------------------------------------------------------------------
__global__ __launch_bounds__(256) void gemm_kernel(
    const u16* __restrict__ outer,  // [16384][640] bf16
    const u16* __restrict__ opWt,   // [128][640] bf16 (o-major)
    const float* __restrict__ opB,
    const u16* __restrict__ embWt,  // [32][128] bf16 (j-major)
    const float* __restrict__ embB,
    const float* __restrict__ w5,   // [32][8] packed head weights
    const float* __restrict__ b5,   // [8] head biases
    float* __restrict__ head8) {
  __shared__ char smem[40960];
  const int tid = threadIdx.x;
  const int w = tid >> 6, lane = tid & 63;
  const int p0 = blockIdx.x * 32;
  const int lr = lane >> 3, lc = lane & 7;
  const int gsw = lc ^ lr;  // swizzled fetch group for A staging
  const int m = lane & 31, kh = lane >> 5;

  f32x16 acc;
#pragma unroll
  for (int r = 0; r < 16; r++) acc[r] = 0.f;

  const u16* gA = outer + (size_t)(p0 + w * 8 + lr) * 640 + gsw * 8;
#pragma unroll
  for (int cc = 0; cc < 10; cc++)
    gload_lds16(gA + cc * 64, smem + cc * 4096 + w * 1024);
  __syncthreads();

  const u16* gB = opWt + (size_t)(w * 32 + m) * 640;
#pragma unroll
  for (int cc = 0; cc < 10; cc++) {
#pragma unroll
    for (int s = 0; s < 4; s++) {
      int pg = (s * 2 + kh) ^ (m & 7);
      bf16x8 av = *(bf16x8*)(smem + cc * 4096 + m * 128 + pg * 16);
      bf16x8 bv = *(const bf16x8*)(gB + cc * 64 + s * 16 + kh * 8);
      acc = __builtin_amdgcn_mfma_f32_32x32x16_bf16(av, bv, acc, 0, 0, 0);
    }
  }
  __syncthreads();  // all waves done reading A before fTile overwrites it

  // ---- epilogue: bias+relu -> bf16 fTile (smem 0..8192, swizzled) ----
  const int o = w * 32 + m;
  float bo = opB[o];
  // stage embWt (32 rows x 128 bf16 = 8KB) into smem+8192, swizzled
#pragma unroll
  for (int i = 0; i < 2; i++) {
    int j = w * 8 + i * 4 + (lane >> 4);
    int ge = (lane & 15) ^ (j & 7);
    gload_lds16(embWt + j * 128 + ge * 8, smem + 8192 + w * 2048 + i * 1024);
  }
  u16* sFb = (u16*)smem;
#pragma unroll
  for (int r = 0; r < 16; r++) {
    int mm = (r & 3) + 8 * (r >> 2) + 4 * kh;
    float v = fmaxf(acc[r] + bo, 0.f);
    int pg = (o >> 3) ^ (mm & 7);
    sFb[mm * 128 + pg * 8 + (o & 7)] = to_bf16(v);
  }
  __syncthreads();

  // ---- emb MFMA: D2[p][j] = fTile(32x128) @ embWt^T(128x32), k split over
  // waves (wave w -> ksteps 2w, 2w+1), partials reduced via LDS ----
  f32x16 acc2;
#pragma unroll
  for (int r = 0; r < 16; r++) acc2[r] = 0.f;
#pragma unroll
  for (int t2 = 0; t2 < 2; t2++) {
    int gg = (w * 2 + t2) * 2 + kh;  // 16B group 0..15
    int pg = gg ^ (m & 7);
    bf16x8 av = *(bf16x8*)(smem + m * 256 + pg * 16);
    bf16x8 bv = *(bf16x8*)(smem + 8192 + m * 256 + pg * 16);
    acc2 = __builtin_amdgcn_mfma_f32_32x32x16_bf16(av, bv, acc2, 0, 0, 0);
  }
  float* scr = (float*)(smem + 16384) + w * 1024;
#pragma unroll
  for (int r = 0; r < 16; r++) {
    int mm = (r & 3) + 8 * (r >> 2) + 4 * kh;
    scr[mm * 32 + m] = acc2[r];
  }
  __syncthreads();

  // reduce 4 partials + bias + relu -> sE[p][36]
  {
    float* sc = (float*)(smem + 16384);
    int i4 = tid * 4;
    float4 v0 = *(float4*)(sc + i4);
    float4 v1 = *(float4*)(sc + 1024 + i4);
    float4 v2 = *(float4*)(sc + 2048 + i4);
    float4 v3 = *(float4*)(sc + 3072 + i4);
    int pp = tid >> 3, j0 = (tid & 7) * 4;
    float4 eb = *(const float4*)(embB + j0);
    float4 e;
    e.x = fmaxf(v0.x + v1.x + v2.x + v3.x + eb.x, 0.f);
    e.y = fmaxf(v0.y + v1.y + v2.y + v3.y + eb.y, 0.f);
    e.z = fmaxf(v0.z + v1.z + v2.z + v3.z + eb.z, 0.f);
    e.w = fmaxf(v0.w + v1.w + v2.w + v3.w + eb.w, 0.f);
    *(float4*)((float*)smem + pp * 36 + j0) = e;
  }
  __syncthreads();

  // heads: 5 heads x 32 points
  if (tid < 160) {
    int h = tid >> 5, p = tid & 31;
    const float* sE = (const float*)smem + p * 36;
    float a = b5[h];
#pragma unroll
    for (int j = 0; j < 32; j++) a = fmaf(sE[j], w5[j * 8 + h], a);
    a = fmaxf(a, 0.f);
    int slot = (h < 2) ? (h + 4) : (h - 2);  // beta->4 satt->5 catt->0 nf0->1 nf1->2
    head8[(size_t)(p0 + p) * 8 + slot] = a;
  }
}

// ---------------------------------------------------------------------------
// Kernel E: stage-2 coords + gaussians + gw + softmax attention -> out (B,L,2)
// block = 256 (4 points x 64 lanes), grid = 4096.
// Precision columns loaded per-lane from global; no sPrec staging barrier.
// ---------------------------------------------------------------------------
__global__ __launch_bounds__(256) void stage2_kernel(
    const float* __restrict__ frames, const int* __restrict__ aaidx,
    const float* __restrict__ cen2, const float* __restrict__ prec2,
    const float* __restrict__ emb2W, const float* __restrict__ emb2B,
    const int* __restrict__ idx32, const float* __restrict__ head8,
    float* __restrict__ out) {
  __shared__ float sCoord[4 * 32 * 5];
  __shared__ float sG2[4 * 32 * 33];
  const int tid = threadIdx.x;
  const int pt = tid >> 6, lane = tid & 63;
  const int pid = blockIdx.x * 4 + pt;
  const int b = pid >> 11;
  const int g = lane & 31;

  float pr[5][5], cn[5];
#pragma unroll
  for (int d = 0; d < 5; d++) {
    cn[d] = cen2[d * 32 + g];
#pragma unroll
    for (int kk = 0; kk < 5; kk++) pr[d][kk] = prec2[(d * 5 + kk) * 32 + g];
  }

  float4 hv = make_float4(0.f, 0.f, 0.f, 0.f);
  float betaS = 0.f, sattS = 0.f;
  if (lane < 32) {
    int n = lane;
    int j = idx32[pid * 32 + n];
    int jg = b * NL + j;
    const float* fs = frames + (size_t)pid * 12;
    const float* fj = frames + (size_t)jg * 12;
    float4 A0 = *(const float4*)(fs);
    float4 A2 = *(const float4*)(fs + 8);
    float4 B0 = *(const float4*)(fj);
    float4 B2 = *(const float4*)(fj + 8);
    float dx = B0.x - A0.x, dy = B0.y - A0.y, dzc = B0.z - A0.z;
    float a2x = A2.y, a2y = A2.z, a2z = A2.w;  // z_i
    float zjx = B2.y, zjy = B2.z, zjz = B2.w;
    float dd = dx * dx + dy * dy + dzc * dzc + 1e-12f;
    float dist = sqrtf(dd);
    float zz = a2x * zjx + a2y * zjy + a2z * zjz;
    float dzv = (dx * zjx + dy * zjy + dzc * zjz) / dist;
    float zdv = (a2x * dx + a2y * dy + a2z * dzc) / dist;
    float si = (float)aaidx[pid];
    float sj = (float)aaidx[jg];
    float idist = fminf(fabsf(sj - si), 8.0f);
    float* cr = sCoord + pt * 160 + n * 5;
    cr[0] = dist; cr[1] = zz; cr[2] = dzv; cr[3] = zdv; cr[4] = idist;
    hv = *(const float4*)(head8 + (size_t)jg * 8);  // catt, nf0, nf1
    betaS = head8[(size_t)pid * 8 + 4];
    sattS = head8[(size_t)pid * 8 + 5];
  }
  __syncthreads();
  {
    const int nh = lane >> 5;
#pragma unroll
    for (int i = 0; i < 16; i++) {
      int n = nh * 16 + i;
      const float* cr = sCoord + pt * 160 + n * 5;
      float df[5];
#pragma unroll
      for (int d = 0; d < 5; d++) df[d] = cr[d] - cn[d];
      float s = 0.0f;
#pragma unroll
      for (int kk = 0; kk < 5; kk++) {
        float y = 0.0f;
#pragma unroll
        for (int d = 0; d < 5; d++) y = fmaf(df[d], pr[d][kk], y);
        s = fmaf(y, y, s);
      }
      sG2[pt * 1056 + n * 33 + g] = __expf(-0.5f * s);
    }
  }
  __syncthreads();
  if (lane < 32) {
    int n = lane;
    float gw = emb2B[0];
#pragma unroll 8
    for (int gg = 0; gg < 32; gg++)
      gw = fmaf(sG2[pt * 1056 + n * 33 + gg], emb2W[gg], gw);
    gw = fmaxf(gw, 0.0f);
    float e = (n == 0) ? sattS : hv.x;
    float logit = betaS * e;
    float mx = logit;
#pragma unroll
    for (int d = 1; d < 32; d <<= 1) mx = fmaxf(mx, __shfl_xor(mx, d, 64));
    float wv = gw * __expf(logit - mx);
    float S = wv;
#pragma unroll
    for (int d = 1; d < 32; d <<= 1) S += __shfl_xor(S, d, 64);
    float a = wv / (S + 1e-6f);
    float o0 = a * hv.y, o1 = a * hv.z;
#pragma unroll
    for (int d = 1; d < 32; d <<= 1) {
      o0 += __shfl_xor(o0, d, 64);
      o1 += __shfl_xor(o1, d, 64);
    }
    if (n == 0) {
      out[pid * 2 + 0] = o0;
      out[pid * 2 + 1] = o1;
    }
  }
}

// ---------------------------------------------------------------------------
extern "C" void kernel_launch(void* const* d_in, const int* in_sizes, int n_in,
                              void* d_out, int out_size, void* d_ws, size_t ws_size,
                              hipStream_t stream) {
  const float* attrs = (const float*)d_in[0];
  const float* frames = (const float*)d_in[1];
  const int* aaidx = (const int*)d_in[2];
  const float* cen1 = (const float*)d_in[3];
  const float* prec1 = (const float*)d_in[4];
  const float* opW = (const float*)d_in[5];
  const float* opB = (const float*)d_in[6];
  const float* embW = (const float*)d_in[7];
  const float* embB = (const float*)d_in[8];
  const float* betaW = (const float*)d_in[9];
  const float* betaB = (const float*)d_in[10];
  const float* sattW = (const float*)d_in[11];
  const float* sattB = (const float*)d_in[12];
  const float* cattW = (const float*)d_in[13];
  const float* cattB = (const float*)d_in[14];
  const float* nodW = (const float*)d_in[15];
  const float* nodB = (const float*)d_in[16];
  const float* cen2 = (const float*)d_in[17];
  const float* prec2 = (const float*)d_in[18];
  const float* emb2W = (const float*)d_in[19];
  const float* emb2B = (const float*)d_in[20];
  float* out = (float*)d_out;

  char* ws = (char*)d_ws;
  int* idx32 = (int*)ws;                              // 2 MiB
  u16* outer_bf = (u16*)(ws + 2097152);               // 16384*640*2 = 20 MiB
  float* head8 = (float*)(ws + 23068672);             // 512 KiB
  u16* opWt = (u16*)(ws + 23592960);                  // 160 KiB
  u16* embWt = (u16*)(ws + 23756800);                 // 8 KiB
  float* w5 = (float*)(ws + 23764992);                // 1 KiB
  float* b5 = (float*)(ws + 23766016);                // 32 B

  knn_prep_kernel<<<dim3(2059), dim3(512), 0, stream>>>(
      frames, idx32, opW, embW, betaW, sattW, cattW, nodW, betaB, sattB,
      cattB, nodB, opWt, embWt, w5, b5);
  stage1_kernel<<<dim3(4096), dim3(256), 0, stream>>>(frames, attrs, aaidx, cen1,
                                                      prec1, idx32, outer_bf);
  gemm_kernel<<<dim3(512), dim3(256), 0, stream>>>(outer_bf, opWt, opB, embWt,
                                                   embB, w5, b5, head8);
  stage2_kernel<<<dim3(4096), dim3(256), 0, stream>>>(frames, aaidx, cen2, prec2,
                                                      emb2W, emb2B, idx32, head8, out);
}